// Round 6
// baseline (817.365 us; speedup 1.0000x reference)
//
#include <hip/hip_runtime.h>

#define N_NODES 100000
#define N_EDGES 3200000
#define N_GRAPHS 64
#define F 16

#define NBUCK 256
#define CPB 391                 // cols per bucket: 256*391 = 100096 >= N_NODES
#define NSL 8                   // row slices (one per XCD)
#define SLROWS 12500            // rows per slice: 8*12500 = 100000 exactly
#define NB2 (NBUCK * NSL)       // 2048 (bucket,slice) chunks
#define NBLK 512                // sort blocks
#define EPB ((N_EDGES + NBLK - 1) / NBLK)   // 6250 edges per block
#define POOL_CHUNK 64
#define GU 4                    // gather ILP unroll

// Pass 1: per-block col-bucket histogram (LDS) -> cntmat[bucket][block]; deg atomics ride along
__global__ __launch_bounds__(256) void k_hist2(const int* __restrict__ row,
                                               const int* __restrict__ col,
                                               int* __restrict__ deg,
                                               int* __restrict__ cntmat) {
    __shared__ int lh[NBUCK];
    for (int i = threadIdx.x; i < NBUCK; i += 256) lh[i] = 0;
    __syncthreads();
    int beg = blockIdx.x * EPB;
    int end = beg + EPB; if (end > N_EDGES) end = N_EDGES;
    for (int e = beg + threadIdx.x; e < end; e += 256) {
        atomicAdd(&deg[row[e]], 1);
        atomicAdd(&lh[(unsigned)col[e] / CPB], 1);
    }
    __syncthreads();
    for (int i = threadIdx.x; i < NBUCK; i += 256)
        cntmat[i * NBLK + blockIdx.x] = lh[i];
}

// Pass 2: per-bucket exclusive scan across blocks
__global__ __launch_bounds__(256) void k_colscan(int* __restrict__ cntmat,
                                                 int* __restrict__ bhist) {
    __shared__ int sd[256];
    int b = blockIdx.x, t = threadIdx.x;
    int a0 = cntmat[b * NBLK + 2 * t];
    int a1 = cntmat[b * NBLK + 2 * t + 1];
    int ps = a0 + a1;
    sd[t] = ps;
    __syncthreads();
    for (int off = 1; off < 256; off <<= 1) {
        int v = (t >= off) ? sd[t - off] : 0;
        __syncthreads();
        sd[t] += v;
        __syncthreads();
    }
    int excl = sd[t] - ps;
    cntmat[b * NBLK + 2 * t] = excl;
    cntmat[b * NBLK + 2 * t + 1] = excl + a0;
    if (t == 255) bhist[b] = sd[255];
}

// Pass 3: exclusive scan of 16-padded bucket totals -> 64B-aligned bases
__global__ __launch_bounds__(256) void k_bscan(const int* __restrict__ bhist,
                                               int* __restrict__ bbase) {
    __shared__ int sd[NBUCK];
    int t = threadIdx.x;
    int v = (bhist[t] + 15) & ~15;
    sd[t] = v;
    __syncthreads();
    for (int off = 1; off < NBUCK; off <<= 1) {
        int a = (t >= off) ? sd[t - off] : 0;
        __syncthreads();
        sd[t] += a;
        __syncthreads();
    }
    bbase[t] = sd[t] - v;
}

// Pass 4: deterministic scatter into col-bucket-grouped recs
// rec = (localcol << 17) | row
__global__ __launch_bounds__(256) void k_fill2(const int* __restrict__ row,
                                               const int* __restrict__ col,
                                               const int* __restrict__ cntmat,
                                               const int* __restrict__ bbase,
                                               unsigned* __restrict__ recs) {
    __shared__ int ptr[NBUCK];
    for (int i = threadIdx.x; i < NBUCK; i += 256)
        ptr[i] = bbase[i] + cntmat[i * NBLK + blockIdx.x];
    __syncthreads();
    int beg = blockIdx.x * EPB;
    int end = beg + EPB; if (end > N_EDGES) end = N_EDGES;
    for (int e = beg + threadIdx.x; e < end; e += 256) {
        unsigned c = (unsigned)col[e];
        unsigned r = (unsigned)row[e];
        unsigned b = c / CPB;
        int slot = atomicAdd(&ptr[b], 1);
        recs[slot] = ((c - b * CPB) << 17) | r;
    }
}

// Pass 5: within each col-bucket, split records into 8 row-slices (in-L2 re-pass)
__global__ __launch_bounds__(256) void k_slice(const unsigned* __restrict__ recsA,
                                               const int* __restrict__ bbase,
                                               const int* __restrict__ bhist,
                                               unsigned* __restrict__ recsB,
                                               int* __restrict__ sbase,
                                               int* __restrict__ scnt) {
    __shared__ int h8[NSL], off8[NSL];
    int b = blockIdx.x;
    if (threadIdx.x < NSL) h8[threadIdx.x] = 0;
    __syncthreads();
    int beg = bbase[b], n = bhist[b];
    for (int i = threadIdx.x; i < n; i += 256) {
        int r = recsA[beg + i] & 0x1FFFF;
        atomicAdd(&h8[r / SLROWS], 1);
    }
    __syncthreads();
    if (threadIdx.x == 0) {
        int run = 0;
        for (int sl = 0; sl < NSL; ++sl) {
            off8[sl] = run;
            sbase[b * NSL + sl] = beg + run;
            scnt[b * NSL + sl] = h8[sl];
            run += h8[sl];
        }
    }
    __syncthreads();
    for (int i = threadIdx.x; i < n; i += 256) {
        unsigned rec = recsA[beg + i];
        int sl = (rec & 0x1FFFF) / SLROWS;
        recsB[beg + atomicAdd(&off8[sl], 1)] = rec;
    }
}

__global__ __launch_bounds__(256) void k_dinv(const int* __restrict__ deg,
                                              float* __restrict__ dinv) {
    int i = blockIdx.x * blockDim.x + threadIdx.x;
    if (i >= N_NODES) return;
    int d = deg[i];
    dinv[i] = d > 0 ? rsqrtf((float)d) : 0.0f;
}

// conv1 node transform: center = x@W1+b1, xj = x@W2   (3 -> 16)
__global__ __launch_bounds__(256) void k_node1(const float* __restrict__ x,
                                               const float* __restrict__ W1,
                                               const float* __restrict__ b1,
                                               const float* __restrict__ W2,
                                               float* __restrict__ center,
                                               float* __restrict__ xj) {
    int t = blockIdx.x * blockDim.x + threadIdx.x;
    if (t >= N_NODES * F) return;
    int n = t >> 4, k = t & 15;
    float x0 = x[n * 3 + 0], x1 = x[n * 3 + 1], x2 = x[n * 3 + 2];
    center[t] = b1[k] + x0 * W1[0 * F + k] + x1 * W1[1 * F + k] + x2 * W1[2 * F + k];
    xj[t]     =         x0 * W2[0 * F + k] + x1 * W2[1 * F + k] + x2 * W2[2 * F + k];
}

// Gather v3: one block per (col-bucket, row-slice); xj reads confined to an
// 800KB slice -> XCD-local L2 hits (blockIdx%8 == slice). Partial tiles out.
__global__ __launch_bounds__(256) void k_gather2(const unsigned* __restrict__ recs2,
                                                 const int* __restrict__ sbase,
                                                 const int* __restrict__ scnt,
                                                 const float* __restrict__ dinv,
                                                 const float* __restrict__ xj,
                                                 float* __restrict__ part,
                                                 int* __restrict__ pct) {
    __shared__ float st[CPB * 17];   // 391 x 16 (+1 stride pad)
    __shared__ int ct[CPB];
    int b2 = blockIdx.x;
    for (int i = threadIdx.x; i < CPB * 17; i += 256) st[i] = 0.0f;
    for (int i = threadIdx.x; i < CPB; i += 256) ct[i] = 0;
    __syncthreads();
    int beg = sbase[b2], end = beg + scnt[b2];
    int g = threadIdx.x >> 4, lane = threadIdx.x & 15;   // 16 groups of 16 lanes
    for (int j0 = beg + g; j0 < end; j0 += 16 * GU) {
        unsigned rc[GU]; float w[GU]; float v[GU]; bool ok[GU];
#pragma unroll
        for (int u = 0; u < GU; ++u) {
            int j = j0 + u * 16;
            ok[u] = j < end;
            rc[u] = recs2[ok[u] ? j : beg];
        }
#pragma unroll
        for (int u = 0; u < GU; ++u) {
            int r = rc[u] & 0x1FFFF;
            w[u] = dinv[r];
            v[u] = xj[r * F + lane];
        }
#pragma unroll
        for (int u = 0; u < GU; ++u) {
            if (ok[u]) {
                int lc = rc[u] >> 17;
                atomicAdd(&st[lc * 17 + lane], w[u] * v[u]);
                if (lane == 0) atomicAdd(&ct[lc], 1);
            }
        }
    }
    __syncthreads();
    size_t pb = (size_t)b2 * (CPB * F);
    for (int i = threadIdx.x; i < CPB * F; i += 256)
        part[pb + i] = st[(i >> 4) * 17 + (i & 15)];
    for (int i = threadIdx.x; i < CPB; i += 256)
        pct[b2 * CPB + i] = ct[i];
}

// combine 8 slice-partials -> s[n,k] = dinv[n]/max(cnt,1) * sum_sl psum
__global__ __launch_bounds__(256) void k_reduce(const float* __restrict__ part,
                                                const int* __restrict__ pct,
                                                const float* __restrict__ dinv,
                                                float* __restrict__ s_out) {
    int t = blockIdx.x * blockDim.x + threadIdx.x;
    if (t >= N_NODES * F) return;
    int n = t >> 4, k = t & 15;
    int colb = n / CPB, lc = n - colb * CPB;
    float acc = 0.0f; int c = 0;
#pragma unroll
    for (int sl = 0; sl < NSL; ++sl) {
        int b2 = colb * NSL + sl;
        acc += part[(size_t)b2 * (CPB * F) + lc * F + k];
        c += pct[b2 * CPB + lc];
    }
    s_out[t] = acc * dinv[n] / (float)(c > 1 ? c : 1);
}

// fallback gather (round-5 version: feature-split, no slicing)
__global__ __launch_bounds__(1024) void k_gather(const unsigned* __restrict__ recs,
                                                 const int* __restrict__ bbase,
                                                 const int* __restrict__ bhist,
                                                 const float* __restrict__ dinv,
                                                 const float* __restrict__ xj,
                                                 float* __restrict__ s_out) {
    __shared__ float st[CPB * 9];
    __shared__ int ct[CPB];
    int b = blockIdx.x >> 1;
    int fbase = (blockIdx.x & 1) * 8;
    for (int i = threadIdx.x; i < CPB * 9; i += 1024) st[i] = 0.0f;
    for (int i = threadIdx.x; i < CPB; i += 1024) ct[i] = 0;
    __syncthreads();
    int beg = bbase[b], end = beg + bhist[b];
    int g = threadIdx.x >> 3, lane8 = threadIdx.x & 7;
    for (int j0 = beg + g; j0 < end; j0 += 128 * GU) {
        unsigned rc[GU]; float w[GU]; float v[GU]; bool ok[GU];
#pragma unroll
        for (int u = 0; u < GU; ++u) {
            int j = j0 + u * 128;
            ok[u] = j < end;
            rc[u] = recs[ok[u] ? j : beg];
        }
#pragma unroll
        for (int u = 0; u < GU; ++u) {
            int r = rc[u] & 0x1FFFF;
            w[u] = dinv[r];
            v[u] = xj[r * F + fbase + lane8];
        }
#pragma unroll
        for (int u = 0; u < GU; ++u) {
            if (ok[u]) {
                int lc = rc[u] >> 17;
                atomicAdd(&st[lc * 9 + lane8], w[u] * v[u]);
                if (lane8 == 0) atomicAdd(&ct[lc], 1);
            }
        }
    }
    __syncthreads();
    for (int i = threadIdx.x; i < CPB * 2; i += 1024) {
        int lc = i >> 1, q = i & 1;
        int n = b * CPB + lc;
        if (n >= N_NODES) continue;
        int c = ct[lc];
        float scale = dinv[n] / (float)(c > 1 ? c : 1);
        float4 o;
        o.x = st[lc * 9 + q * 4 + 0] * scale;
        o.y = st[lc * 9 + q * 4 + 1] * scale;
        o.z = st[lc * 9 + q * 4 + 2] * scale;
        o.w = st[lc * 9 + q * 4 + 3] * scale;
        ((float4*)(s_out + n * F + fbase))[q] = o;
    }
}

// finalize conv1 (relu(center + s)) then conv2 node transform (16->16)
__global__ __launch_bounds__(256) void k_node2(float* center_io, const float* __restrict__ s,
                                               const float* __restrict__ W1,
                                               const float* __restrict__ b1,
                                               const float* __restrict__ W2,
                                               float* xj_io) {
    int n = blockIdx.x * blockDim.x + threadIdx.x;
    if (n >= N_NODES) return;
    float h[F];
#pragma unroll
    for (int k = 0; k < F; ++k) {
        float v = center_io[n * F + k] + s[n * F + k];
        h[k] = v > 0.0f ? v : 0.0f;
    }
#pragma unroll
    for (int k = 0; k < F; ++k) {
        float c2 = b1[k];
        float x2 = 0.0f;
#pragma unroll
        for (int i = 0; i < F; ++i) {
            c2 += h[i] * W1[i * F + k];
            x2 += h[i] * W2[i * F + k];
        }
        center_io[n * F + k] = c2;
        xj_io[n * F + k] = x2;
    }
}

// run-length pooling over sorted batch
__global__ __launch_bounds__(256) void k_pool(const float* __restrict__ center,
                                              const float* __restrict__ s,
                                              const int* __restrict__ batch,
                                              float* __restrict__ gpool,
                                              int* __restrict__ gcnt) {
    int t = blockIdx.x * blockDim.x + threadIdx.x;
    int gid = t >> 4, k = t & 15;
    int n0 = gid * POOL_CHUNK;
    if (n0 >= N_NODES) return;
    int n1 = n0 + POOL_CHUNK; if (n1 > N_NODES) n1 = N_NODES;
    int bcur = batch[n0];
    float acc = 0.0f; int run = 0;
    for (int n = n0; n < n1; ++n) {
        int b = batch[n];
        if (b != bcur) {
            atomicAdd(&gpool[bcur * F + k], acc);
            if (k == 0) atomicAdd(&gcnt[bcur], run);
            acc = 0.0f; run = 0; bcur = b;
        }
        float h = center[n * F + k] + s[n * F + k];
        acc += h > 0.0f ? h : 0.0f;
        ++run;
    }
    atomicAdd(&gpool[bcur * F + k], acc);
    if (k == 0) atomicAdd(&gcnt[bcur], run);
}

__global__ __launch_bounds__(64) void k_mlp(const float* __restrict__ gpool,
                                            const int* __restrict__ gcnt,
                                            const float* __restrict__ l1W,
                                            const float* __restrict__ l1b,
                                            const float* __restrict__ l2W,
                                            const float* __restrict__ l2b,
                                            float* __restrict__ out) {
    int g = threadIdx.x;
    if (g >= N_GRAPHS) return;
    int c = gcnt[g];
    float ic = 1.0f / (float)(c > 1 ? c : 1);
    float v[F], h[F];
#pragma unroll
    for (int k = 0; k < F; ++k) v[k] = gpool[g * F + k] * ic;
#pragma unroll
    for (int k = 0; k < F; ++k) {
        float a = l1b[k];
#pragma unroll
        for (int i = 0; i < F; ++i) a += v[i] * l1W[i * F + k];
        h[k] = a > 0.0f ? a : 0.0f;
    }
#pragma unroll
    for (int j = 0; j < 2; ++j) {
        float a = l2b[j];
#pragma unroll
        for (int i = 0; i < F; ++i) a += h[i] * l2W[i * 2 + j];
        out[g * 2 + j] = a;
    }
}

extern "C" void kernel_launch(void* const* d_in, const int* in_sizes, int n_in,
                              void* d_out, int out_size, void* d_ws, size_t ws_size,
                              hipStream_t stream) {
    const float* x     = (const float*)d_in[0];
    const int*   ei    = (const int*)d_in[1];
    const int*   row   = ei;
    const int*   col   = ei + N_EDGES;
    const int*   batch = (const int*)d_in[2];
    const float* c1W1  = (const float*)d_in[3];
    const float* c1b1  = (const float*)d_in[4];
    const float* c1W2  = (const float*)d_in[5];
    const float* c2W1  = (const float*)d_in[6];
    const float* c2b1  = (const float*)d_in[7];
    const float* c2W2  = (const float*)d_in[8];
    const float* l1W   = (const float*)d_in[9];
    const float* l1b   = (const float*)d_in[10];
    const float* l2W   = (const float*)d_in[11];
    const float* l2b   = (const float*)d_in[12];
    float* out = (float*)d_out;

    char* p = (char*)d_ws;
    auto alloc = [&p](size_t bytes) -> void* {
        void* r = (void*)p;
        p += (bytes + 255) & ~(size_t)255;
        return r;
    };
    int*      deg    = (int*)     alloc(N_NODES * 4);
    float*    dinv   = (float*)   alloc(N_NODES * 4);
    float*    center = (float*)   alloc((size_t)N_NODES * F * 4);
    float*    xj     = (float*)   alloc((size_t)N_NODES * F * 4);
    float*    s      = (float*)   alloc((size_t)N_NODES * F * 4);
    float*    gpool  = (float*)   alloc(N_GRAPHS * F * 4);
    int*      gcnt   = (int*)     alloc(N_GRAPHS * 4);
    int*      bhist  = (int*)     alloc(NBUCK * 4);
    int*      bbase  = (int*)     alloc((NBUCK + 1) * 4);
    int*      cntmat = (int*)     alloc((size_t)NBUCK * NBLK * 4);
    unsigned* recsA  = (unsigned*)alloc(((size_t)N_EDGES + NBUCK * 16) * 4);
    // extended (sliced) arena
    unsigned* recsB  = (unsigned*)alloc(((size_t)N_EDGES + NBUCK * 16) * 4);
    int*      sbase  = (int*)     alloc(NB2 * 4);
    int*      scnt   = (int*)     alloc(NB2 * 4);
    int*      pct    = (int*)     alloc((size_t)NB2 * CPB * 4);
    float*    part   = (float*)   alloc((size_t)NB2 * CPB * F * 4);
    size_t needed_full = (size_t)(p - (char*)d_ws);
    bool full = ws_size >= needed_full;

    hipMemsetAsync(deg, 0, N_NODES * 4, stream);
    hipMemsetAsync(gpool, 0, N_GRAPHS * F * 4, stream);
    hipMemsetAsync(gcnt, 0, N_GRAPHS * 4, stream);

    k_hist2<<<NBLK, 256, 0, stream>>>(row, col, deg, cntmat);
    k_colscan<<<NBUCK, 256, 0, stream>>>(cntmat, bhist);
    k_bscan<<<1, 256, 0, stream>>>(bhist, bbase);
    k_fill2<<<NBLK, 256, 0, stream>>>(row, col, cntmat, bbase, recsA);
    k_dinv<<<(N_NODES + 255) / 256, 256, 0, stream>>>(deg, dinv);
    k_node1<<<(N_NODES * F + 255) / 256, 256, 0, stream>>>(x, c1W1, c1b1, c1W2, center, xj);

    if (full) {
        k_slice<<<NBUCK, 256, 0, stream>>>(recsA, bbase, bhist, recsB, sbase, scnt);
        k_gather2<<<NB2, 256, 0, stream>>>(recsB, sbase, scnt, dinv, xj, part, pct);
        k_reduce<<<(N_NODES * F + 255) / 256, 256, 0, stream>>>(part, pct, dinv, s);
        k_node2<<<(N_NODES + 255) / 256, 256, 0, stream>>>(center, s, c2W1, c2b1, c2W2, xj);
        k_gather2<<<NB2, 256, 0, stream>>>(recsB, sbase, scnt, dinv, xj, part, pct);
        k_reduce<<<(N_NODES * F + 255) / 256, 256, 0, stream>>>(part, pct, dinv, s);
    } else {
        k_gather<<<NBUCK * 2, 1024, 0, stream>>>(recsA, bbase, bhist, dinv, xj, s);
        k_node2<<<(N_NODES + 255) / 256, 256, 0, stream>>>(center, s, c2W1, c2b1, c2W2, xj);
        k_gather<<<NBUCK * 2, 1024, 0, stream>>>(recsA, bbase, bhist, dinv, xj, s);
    }

    k_pool<<<((N_NODES + POOL_CHUNK - 1) / POOL_CHUNK * 16 + 255) / 256, 256, 0, stream>>>(
        center, s, batch, gpool, gcnt);
    k_mlp<<<1, 64, 0, stream>>>(gpool, gcnt, l1W, l1b, l2W, l2b, out);
}

// Round 7
// 318.055 us; speedup vs baseline: 2.5699x; 2.5699x over previous
//
#include <hip/hip_runtime.h>

#define N_NODES 100000
#define N_EDGES 3200000
#define N_GRAPHS 64
#define F 16

#define NBUCK 256
#define CPB 391                 // cols per bucket: 256*391 = 100096 >= N_NODES
#define NBLK 512                // sort blocks
#define EPB ((N_EDGES + NBLK - 1) / NBLK)   // 6250 edges per block
#define POOL_CHUNK 64
#define RMASK 0x1FFFF

// Pass 1: per-block col-bucket histogram (LDS) -> cntmat[bucket][block]; deg atomics ride along
__global__ __launch_bounds__(256) void k_hist2(const int* __restrict__ row,
                                               const int* __restrict__ col,
                                               int* __restrict__ deg,
                                               int* __restrict__ cntmat) {
    __shared__ int lh[NBUCK];
    for (int i = threadIdx.x; i < NBUCK; i += 256) lh[i] = 0;
    __syncthreads();
    int beg = blockIdx.x * EPB;
    int end = beg + EPB; if (end > N_EDGES) end = N_EDGES;
    for (int e = beg + threadIdx.x; e < end; e += 256) {
        atomicAdd(&deg[row[e]], 1);
        atomicAdd(&lh[(unsigned)col[e] / CPB], 1);
    }
    __syncthreads();
    for (int i = threadIdx.x; i < NBUCK; i += 256)
        cntmat[i * NBLK + blockIdx.x] = lh[i];
}

// Pass 2: per-bucket exclusive scan across blocks
__global__ __launch_bounds__(256) void k_colscan(int* __restrict__ cntmat,
                                                 int* __restrict__ bhist) {
    __shared__ int sd[256];
    int b = blockIdx.x, t = threadIdx.x;
    int a0 = cntmat[b * NBLK + 2 * t];
    int a1 = cntmat[b * NBLK + 2 * t + 1];
    int ps = a0 + a1;
    sd[t] = ps;
    __syncthreads();
    for (int off = 1; off < 256; off <<= 1) {
        int v = (t >= off) ? sd[t - off] : 0;
        __syncthreads();
        sd[t] += v;
        __syncthreads();
    }
    int excl = sd[t] - ps;
    cntmat[b * NBLK + 2 * t] = excl;
    cntmat[b * NBLK + 2 * t + 1] = excl + a0;
    if (t == 255) bhist[b] = sd[255];
}

// Pass 3: exclusive scan of 16-padded bucket totals -> 64B-aligned bases
__global__ __launch_bounds__(256) void k_bscan(const int* __restrict__ bhist,
                                               int* __restrict__ bbase) {
    __shared__ int sd[NBUCK];
    int t = threadIdx.x;
    int v = (bhist[t] + 15) & ~15;
    sd[t] = v;
    __syncthreads();
    for (int off = 1; off < NBUCK; off <<= 1) {
        int a = (t >= off) ? sd[t - off] : 0;
        __syncthreads();
        sd[t] += a;
        __syncthreads();
    }
    bbase[t] = sd[t] - v;
}

// Pass 4: deterministic scatter into col-bucket-grouped recsA; rec = (localcol<<17)|row
__global__ __launch_bounds__(256) void k_fill2(const int* __restrict__ row,
                                               const int* __restrict__ col,
                                               const int* __restrict__ cntmat,
                                               const int* __restrict__ bbase,
                                               unsigned* __restrict__ recs) {
    __shared__ int ptr[NBUCK];
    for (int i = threadIdx.x; i < NBUCK; i += 256)
        ptr[i] = bbase[i] + cntmat[i * NBLK + blockIdx.x];
    __syncthreads();
    int beg = blockIdx.x * EPB;
    int end = beg + EPB; if (end > N_EDGES) end = N_EDGES;
    for (int e = beg + threadIdx.x; e < end; e += 256) {
        unsigned c = (unsigned)col[e];
        unsigned r = (unsigned)row[e];
        unsigned b = c / CPB;
        int slot = atomicAdd(&ptr[b], 1);
        recs[slot] = ((c - b * CPB) << 17) | r;
    }
}

// Pass 5: per-bucket counting sort by local col -> recsB (CSR order) + rowptr + cnt_in
__global__ __launch_bounds__(256) void k_sort391(const unsigned* __restrict__ recsA,
                                                 const int* __restrict__ bbase,
                                                 const int* __restrict__ bhist,
                                                 unsigned* __restrict__ recsB,
                                                 int* __restrict__ rowptr,
                                                 int* __restrict__ cnt_in) {
    __shared__ int hist[CPB];
    __shared__ int scn[512];
    __shared__ int off[CPB];
    int b = blockIdx.x, t = threadIdx.x;
    for (int i = t; i < CPB; i += 256) hist[i] = 0;
    __syncthreads();
    int beg = bbase[b], n = bhist[b];
    for (int i = t; i < n; i += 256)
        atomicAdd(&hist[recsA[beg + i] >> 17], 1);
    __syncthreads();
    scn[t]       = (t < CPB) ? hist[t] : 0;
    scn[t + 256] = (t + 256 < CPB) ? hist[t + 256] : 0;
    __syncthreads();
    for (int o = 1; o < 512; o <<= 1) {
        int v0 = (t >= o) ? scn[t - o] : 0;
        int v1 = (t + 256 >= o) ? scn[t + 256 - o] : 0;
        __syncthreads();
        scn[t] += v0; scn[t + 256] += v1;
        __syncthreads();
    }
    for (int lc = t; lc < CPB; lc += 256) {
        int ex = scn[lc] - hist[lc];
        off[lc] = ex;
        int node = b * CPB + lc;
        if (node < N_NODES) { rowptr[node] = beg + ex; cnt_in[node] = hist[lc]; }
    }
    __syncthreads();
    for (int i = t; i < n; i += 256) {
        unsigned rec = recsA[beg + i];
        int d = atomicAdd(&off[rec >> 17], 1);
        recsB[beg + d] = rec;
    }
}

// dinv + pre-weighted padded source features: wx[n] = dinv[n] * x[n,0..2]
__global__ __launch_bounds__(256) void k_dinvwx(const int* __restrict__ deg,
                                                const float* __restrict__ x,
                                                float* __restrict__ dinv,
                                                float4* __restrict__ wx) {
    int i = blockIdx.x * blockDim.x + threadIdx.x;
    if (i >= N_NODES) return;
    int d = deg[i];
    float di = d > 0 ? rsqrtf((float)d) : 0.0f;
    dinv[i] = di;
    wx[i] = make_float4(di * x[i * 3 + 0], di * x[i * 3 + 1], di * x[i * 3 + 2], 0.0f);
}

// conv1 aggregation in INPUT space (3 feats): y[n] = dinv[n]/max(cnt,1) * sum wx[r]
__global__ __launch_bounds__(256) void k_gather_x(const unsigned* __restrict__ recsB,
                                                  const int* __restrict__ rowptr,
                                                  const int* __restrict__ cnt_in,
                                                  const float* __restrict__ dinv,
                                                  const float4* __restrict__ wx,
                                                  float4* __restrict__ y) {
    int nn = blockIdx.x * blockDim.x + threadIdx.x;
    if (nn >= N_NODES) return;
    int beg = rowptr[nn], c = cnt_in[nn], end = beg + c;
    float a0 = 0.0f, a1 = 0.0f, a2 = 0.0f;
    int j = beg;
    for (; j + 1 < end; j += 2) {
        int r0 = recsB[j] & RMASK, r1 = recsB[j + 1] & RMASK;
        float4 v0 = wx[r0], v1 = wx[r1];
        a0 += v0.x + v1.x; a1 += v0.y + v1.y; a2 += v0.z + v1.z;
    }
    if (j < end) {
        float4 v = wx[recsB[j] & RMASK];
        a0 += v.x; a1 += v.y; a2 += v.z;
    }
    float sc = dinv[nn] / (float)(c > 1 ? c : 1);
    y[nn] = make_float4(a0 * sc, a1 * sc, a2 * sc, 0.0f);
}

// fused: h1 = relu(x@W1+b1 + y@W2); center2 = h1@W1'+b1'; xj2 = dinv * h1@W2'
__global__ __launch_bounds__(256) void k_node12(const float* __restrict__ x,
                                                const float4* __restrict__ y,
                                                const float* __restrict__ c1W1,
                                                const float* __restrict__ c1b1,
                                                const float* __restrict__ c1W2,
                                                const float* __restrict__ c2W1,
                                                const float* __restrict__ c2b1,
                                                const float* __restrict__ c2W2,
                                                const float* __restrict__ dinv,
                                                float* __restrict__ center2,
                                                float* __restrict__ xj2) {
    int nn = blockIdx.x * blockDim.x + threadIdx.x;
    if (nn >= N_NODES) return;
    float x0 = x[nn * 3 + 0], x1 = x[nn * 3 + 1], x2 = x[nn * 3 + 2];
    float4 yy = y[nn];
    float h[F];
#pragma unroll
    for (int k = 0; k < F; ++k) {
        float v = c1b1[k]
                + x0 * c1W1[0 * F + k] + x1 * c1W1[1 * F + k] + x2 * c1W1[2 * F + k]
                + yy.x * c1W2[0 * F + k] + yy.y * c1W2[1 * F + k] + yy.z * c1W2[2 * F + k];
        h[k] = v > 0.0f ? v : 0.0f;
    }
    float di = dinv[nn];
#pragma unroll
    for (int k = 0; k < F; ++k) {
        float c2 = c2b1[k];
        float xx = 0.0f;
#pragma unroll
        for (int i = 0; i < F; ++i) {
            c2 += h[i] * c2W1[i * F + k];
            xx += h[i] * c2W2[i * F + k];
        }
        center2[nn * F + k] = c2;
        xj2[nn * F + k] = di * xx;
    }
}

// conv2 aggregation: 16-lane group per node, lane = feature; register accumulation, no atomics
__global__ __launch_bounds__(256) void k_gather_h(const unsigned* __restrict__ recsB,
                                                  const int* __restrict__ rowptr,
                                                  const int* __restrict__ cnt_in,
                                                  const float* __restrict__ dinv,
                                                  const float* __restrict__ xj2,
                                                  float* __restrict__ s2) {
    int g = threadIdx.x >> 4, k = threadIdx.x & 15;
    int nn = blockIdx.x * 16 + g;
    if (nn >= N_NODES) return;
    int beg = rowptr[nn], c = cnt_in[nn], end = beg + c;
    float acc = 0.0f;
    int j = beg;
    for (; j + 3 < end; j += 4) {
        int r0 = recsB[j] & RMASK, r1 = recsB[j + 1] & RMASK;
        int r2 = recsB[j + 2] & RMASK, r3 = recsB[j + 3] & RMASK;
        float v0 = xj2[r0 * F + k], v1 = xj2[r1 * F + k];
        float v2 = xj2[r2 * F + k], v3 = xj2[r3 * F + k];
        acc += (v0 + v1) + (v2 + v3);
    }
    for (; j < end; ++j) acc += xj2[(recsB[j] & RMASK) * F + k];
    s2[nn * F + k] = acc * dinv[nn] / (float)(c > 1 ? c : 1);
}

// run-length pooling over sorted batch: relu(center2 + s2) summed per graph
__global__ __launch_bounds__(256) void k_pool(const float* __restrict__ center,
                                              const float* __restrict__ s,
                                              const int* __restrict__ batch,
                                              float* __restrict__ gpool,
                                              int* __restrict__ gcnt) {
    int t = blockIdx.x * blockDim.x + threadIdx.x;
    int gid = t >> 4, k = t & 15;
    int n0 = gid * POOL_CHUNK;
    if (n0 >= N_NODES) return;
    int n1 = n0 + POOL_CHUNK; if (n1 > N_NODES) n1 = N_NODES;
    int bcur = batch[n0];
    float acc = 0.0f; int run = 0;
    for (int n = n0; n < n1; ++n) {
        int b = batch[n];
        if (b != bcur) {
            atomicAdd(&gpool[bcur * F + k], acc);
            if (k == 0) atomicAdd(&gcnt[bcur], run);
            acc = 0.0f; run = 0; bcur = b;
        }
        float h = center[n * F + k] + s[n * F + k];
        acc += h > 0.0f ? h : 0.0f;
        ++run;
    }
    atomicAdd(&gpool[bcur * F + k], acc);
    if (k == 0) atomicAdd(&gcnt[bcur], run);
}

__global__ __launch_bounds__(64) void k_mlp(const float* __restrict__ gpool,
                                            const int* __restrict__ gcnt,
                                            const float* __restrict__ l1W,
                                            const float* __restrict__ l1b,
                                            const float* __restrict__ l2W,
                                            const float* __restrict__ l2b,
                                            float* __restrict__ out) {
    int g = threadIdx.x;
    if (g >= N_GRAPHS) return;
    int c = gcnt[g];
    float ic = 1.0f / (float)(c > 1 ? c : 1);
    float v[F], h[F];
#pragma unroll
    for (int k = 0; k < F; ++k) v[k] = gpool[g * F + k] * ic;
#pragma unroll
    for (int k = 0; k < F; ++k) {
        float a = l1b[k];
#pragma unroll
        for (int i = 0; i < F; ++i) a += v[i] * l1W[i * F + k];
        h[k] = a > 0.0f ? a : 0.0f;
    }
#pragma unroll
    for (int j = 0; j < 2; ++j) {
        float a = l2b[j];
#pragma unroll
        for (int i = 0; i < F; ++i) a += h[i] * l2W[i * 2 + j];
        out[g * 2 + j] = a;
    }
}

extern "C" void kernel_launch(void* const* d_in, const int* in_sizes, int n_in,
                              void* d_out, int out_size, void* d_ws, size_t ws_size,
                              hipStream_t stream) {
    const float* x     = (const float*)d_in[0];
    const int*   ei    = (const int*)d_in[1];
    const int*   row   = ei;
    const int*   col   = ei + N_EDGES;
    const int*   batch = (const int*)d_in[2];
    const float* c1W1  = (const float*)d_in[3];
    const float* c1b1  = (const float*)d_in[4];
    const float* c1W2  = (const float*)d_in[5];
    const float* c2W1  = (const float*)d_in[6];
    const float* c2b1  = (const float*)d_in[7];
    const float* c2W2  = (const float*)d_in[8];
    const float* l1W   = (const float*)d_in[9];
    const float* l1b   = (const float*)d_in[10];
    const float* l2W   = (const float*)d_in[11];
    const float* l2b   = (const float*)d_in[12];
    float* out = (float*)d_out;

    char* p = (char*)d_ws;
    auto alloc = [&p](size_t bytes) -> void* {
        void* r = (void*)p;
        p += (bytes + 255) & ~(size_t)255;
        return r;
    };
    int*      deg     = (int*)     alloc(N_NODES * 4);
    float*    dinv    = (float*)   alloc(N_NODES * 4);
    float4*   wx      = (float4*)  alloc((size_t)N_NODES * 16);
    float4*   y       = (float4*)  alloc((size_t)N_NODES * 16);
    float*    center2 = (float*)   alloc((size_t)N_NODES * F * 4);
    float*    xj2     = (float*)   alloc((size_t)N_NODES * F * 4);
    float*    s2      = (float*)   alloc((size_t)N_NODES * F * 4);
    float*    gpool   = (float*)   alloc(N_GRAPHS * F * 4);
    int*      gcnt    = (int*)     alloc(N_GRAPHS * 4);
    int*      bhist   = (int*)     alloc(NBUCK * 4);
    int*      bbase   = (int*)     alloc((NBUCK + 1) * 4);
    int*      cntmat  = (int*)     alloc((size_t)NBUCK * NBLK * 4);
    int*      rowptr  = (int*)     alloc((size_t)N_NODES * 4);
    int*      cnt_in  = (int*)     alloc((size_t)N_NODES * 4);
    unsigned* recsA   = (unsigned*)alloc(((size_t)N_EDGES + NBUCK * 16) * 4);
    unsigned* recsB   = (unsigned*)alloc(((size_t)N_EDGES + NBUCK * 16) * 4);

    hipMemsetAsync(deg, 0, N_NODES * 4, stream);
    hipMemsetAsync(gpool, 0, N_GRAPHS * F * 4, stream);
    hipMemsetAsync(gcnt, 0, N_GRAPHS * 4, stream);

    k_hist2<<<NBLK, 256, 0, stream>>>(row, col, deg, cntmat);
    k_colscan<<<NBUCK, 256, 0, stream>>>(cntmat, bhist);
    k_bscan<<<1, 256, 0, stream>>>(bhist, bbase);
    k_fill2<<<NBLK, 256, 0, stream>>>(row, col, cntmat, bbase, recsA);
    k_sort391<<<NBUCK, 256, 0, stream>>>(recsA, bbase, bhist, recsB, rowptr, cnt_in);
    k_dinvwx<<<(N_NODES + 255) / 256, 256, 0, stream>>>(deg, x, dinv, wx);

    k_gather_x<<<(N_NODES + 255) / 256, 256, 0, stream>>>(recsB, rowptr, cnt_in, dinv, wx, y);
    k_node12<<<(N_NODES + 255) / 256, 256, 0, stream>>>(x, y, c1W1, c1b1, c1W2,
                                                        c2W1, c2b1, c2W2, dinv, center2, xj2);
    k_gather_h<<<(N_NODES + 15) / 16, 256, 0, stream>>>(recsB, rowptr, cnt_in, dinv, xj2, s2);

    k_pool<<<((N_NODES + POOL_CHUNK - 1) / POOL_CHUNK * 16 + 255) / 256, 256, 0, stream>>>(
        center2, s2, batch, gpool, gcnt);
    k_mlp<<<1, 64, 0, stream>>>(gpool, gcnt, l1W, l1b, l2W, l2b, out);
}

// Round 8
// 247.752 us; speedup vs baseline: 3.2991x; 1.2838x over previous
//
#include <hip/hip_runtime.h>

#define N_NODES 100000
#define N_EDGES 3200000
#define N_GRAPHS 64
#define F 16

#define NBUCK 256
#define CPB 391                 // cols per bucket: 256*391 = 100096 >= N_NODES
#define NBLK 512                // sort blocks
#define EPB ((N_EDGES + NBLK - 1) / NBLK)   // 6250 edges per block
#define POOL_CHUNK 64
#define RMASK 0x1FFFF

// Pass 1: per-block LDS histograms of BOTH col-buckets and row-buckets (no global atomics)
__global__ __launch_bounds__(256) void k_histAB(const int* __restrict__ row,
                                                const int* __restrict__ col,
                                                int* __restrict__ cntmatC,
                                                int* __restrict__ cntmatR) {
    __shared__ int lhc[NBUCK], lhr[NBUCK];
    for (int i = threadIdx.x; i < NBUCK; i += 256) { lhc[i] = 0; lhr[i] = 0; }
    __syncthreads();
    int beg = blockIdx.x * EPB;
    int end = beg + EPB; if (end > N_EDGES) end = N_EDGES;
    for (int e = beg + threadIdx.x; e < end; e += 256) {
        atomicAdd(&lhc[(unsigned)col[e] / CPB], 1);
        atomicAdd(&lhr[(unsigned)row[e] / CPB], 1);
    }
    __syncthreads();
    for (int i = threadIdx.x; i < NBUCK; i += 256) {
        cntmatC[i * NBLK + blockIdx.x] = lhc[i];
        cntmatR[i * NBLK + blockIdx.x] = lhr[i];
    }
}

// Pass 2: per-bucket exclusive scan across blocks (blocks 0-255: col, 256-511: row)
__global__ __launch_bounds__(256) void k_colscan2(int* __restrict__ cntmatC,
                                                  int* __restrict__ cntmatR,
                                                  int* __restrict__ bhistC,
                                                  int* __restrict__ bhistR) {
    __shared__ int sd[256];
    int which = blockIdx.x >> 8;
    int b = blockIdx.x & 255, t = threadIdx.x;
    int* cm = which ? cntmatR : cntmatC;
    int* bh = which ? bhistR : bhistC;
    int a0 = cm[b * NBLK + 2 * t];
    int a1 = cm[b * NBLK + 2 * t + 1];
    int ps = a0 + a1;
    sd[t] = ps;
    __syncthreads();
    for (int off = 1; off < 256; off <<= 1) {
        int v = (t >= off) ? sd[t - off] : 0;
        __syncthreads();
        sd[t] += v;
        __syncthreads();
    }
    int excl = sd[t] - ps;
    cm[b * NBLK + 2 * t] = excl;
    cm[b * NBLK + 2 * t + 1] = excl + a0;
    if (t == 255) bh[b] = sd[255];
}

// Pass 3: exclusive scan of 16-padded bucket totals (block 0: col, block 1: row)
__global__ __launch_bounds__(256) void k_bscan2(const int* __restrict__ bhistC,
                                                const int* __restrict__ bhistR,
                                                int* __restrict__ bbaseC,
                                                int* __restrict__ bbaseR) {
    __shared__ int sd[NBUCK];
    const int* h = blockIdx.x == 0 ? bhistC : bhistR;
    int* o = blockIdx.x == 0 ? bbaseC : bbaseR;
    int t = threadIdx.x;
    int v = (h[t] + 15) & ~15;
    sd[t] = v;
    __syncthreads();
    for (int off = 1; off < NBUCK; off <<= 1) {
        int a = (t >= off) ? sd[t - off] : 0;
        __syncthreads();
        sd[t] += a;
        __syncthreads();
    }
    o[t] = sd[t] - v;
}

// Pass 4: dual deterministic scatter: col-grouped recsA + row-bucket-grouped rrecs tokens
__global__ __launch_bounds__(256) void k_fill3(const int* __restrict__ row,
                                               const int* __restrict__ col,
                                               const int* __restrict__ cntmatC,
                                               const int* __restrict__ cntmatR,
                                               const int* __restrict__ bbaseC,
                                               const int* __restrict__ bbaseR,
                                               unsigned* __restrict__ recsA,
                                               unsigned short* __restrict__ rrecs) {
    __shared__ int ptrC[NBUCK], ptrR[NBUCK];
    for (int i = threadIdx.x; i < NBUCK; i += 256) {
        ptrC[i] = bbaseC[i] + cntmatC[i * NBLK + blockIdx.x];
        ptrR[i] = bbaseR[i] + cntmatR[i * NBLK + blockIdx.x];
    }
    __syncthreads();
    int beg = blockIdx.x * EPB;
    int end = beg + EPB; if (end > N_EDGES) end = N_EDGES;
    for (int e = beg + threadIdx.x; e < end; e += 256) {
        unsigned c = (unsigned)col[e];
        unsigned r = (unsigned)row[e];
        unsigned bc = c / CPB;
        int slot = atomicAdd(&ptrC[bc], 1);
        recsA[slot] = ((c - bc * CPB) << 17) | r;
        unsigned br = r / CPB;
        int slotR = atomicAdd(&ptrR[br], 1);
        rrecs[slotR] = (unsigned short)(r - br * CPB);
    }
}

// Pass 5: per-row-bucket 391-bin histogram -> dinv + wx (no deg array, no global atomics)
__global__ __launch_bounds__(256) void k_deg391(const unsigned short* __restrict__ rrecs,
                                                const int* __restrict__ bbaseR,
                                                const int* __restrict__ bhistR,
                                                const float* __restrict__ x,
                                                float* __restrict__ dinv,
                                                float4* __restrict__ wx) {
    __shared__ int hist[CPB];
    int b = blockIdx.x, t = threadIdx.x;
    for (int i = t; i < CPB; i += 256) hist[i] = 0;
    __syncthreads();
    int beg = bbaseR[b], n = bhistR[b];
    for (int i = t; i < n; i += 256)
        atomicAdd(&hist[rrecs[beg + i]], 1);
    __syncthreads();
    for (int lc = t; lc < CPB; lc += 256) {
        int node = b * CPB + lc;
        if (node >= N_NODES) continue;
        int d = hist[lc];
        float di = d > 0 ? rsqrtf((float)d) : 0.0f;
        dinv[node] = di;
        wx[node] = make_float4(di * x[node * 3 + 0], di * x[node * 3 + 1],
                               di * x[node * 3 + 2], 0.0f);
    }
}

// Pass 6: per-col-bucket counting sort by local col -> recsB (CSR order) + rowptr + cnt_in
__global__ __launch_bounds__(256) void k_sort391(const unsigned* __restrict__ recsA,
                                                 const int* __restrict__ bbase,
                                                 const int* __restrict__ bhist,
                                                 unsigned* __restrict__ recsB,
                                                 int* __restrict__ rowptr,
                                                 int* __restrict__ cnt_in) {
    __shared__ int hist[CPB];
    __shared__ int scn[512];
    __shared__ int off[CPB];
    int b = blockIdx.x, t = threadIdx.x;
    for (int i = t; i < CPB; i += 256) hist[i] = 0;
    __syncthreads();
    int beg = bbase[b], n = bhist[b];
    for (int i = t; i < n; i += 256)
        atomicAdd(&hist[recsA[beg + i] >> 17], 1);
    __syncthreads();
    scn[t]       = (t < CPB) ? hist[t] : 0;
    scn[t + 256] = (t + 256 < CPB) ? hist[t + 256] : 0;
    __syncthreads();
    for (int o = 1; o < 512; o <<= 1) {
        int v0 = (t >= o) ? scn[t - o] : 0;
        int v1 = (t + 256 >= o) ? scn[t + 256 - o] : 0;
        __syncthreads();
        scn[t] += v0; scn[t + 256] += v1;
        __syncthreads();
    }
    for (int lc = t; lc < CPB; lc += 256) {
        int ex = scn[lc] - hist[lc];
        off[lc] = ex;
        int node = b * CPB + lc;
        if (node < N_NODES) { rowptr[node] = beg + ex; cnt_in[node] = hist[lc]; }
    }
    __syncthreads();
    for (int i = t; i < n; i += 256) {
        unsigned rec = recsA[beg + i];
        int d = atomicAdd(&off[rec >> 17], 1);
        recsB[beg + d] = rec;
    }
}

// conv1 aggregation in INPUT space (3 feats): y[n] = dinv[n]/max(cnt,1) * sum wx[r]
__global__ __launch_bounds__(256) void k_gather_x(const unsigned* __restrict__ recsB,
                                                  const int* __restrict__ rowptr,
                                                  const int* __restrict__ cnt_in,
                                                  const float* __restrict__ dinv,
                                                  const float4* __restrict__ wx,
                                                  float4* __restrict__ y) {
    int nn = blockIdx.x * blockDim.x + threadIdx.x;
    if (nn >= N_NODES) return;
    int beg = rowptr[nn], c = cnt_in[nn], end = beg + c;
    float a0 = 0.0f, a1 = 0.0f, a2 = 0.0f;
    int j = beg;
    for (; j + 1 < end; j += 2) {
        int r0 = recsB[j] & RMASK, r1 = recsB[j + 1] & RMASK;
        float4 v0 = wx[r0], v1 = wx[r1];
        a0 += v0.x + v1.x; a1 += v0.y + v1.y; a2 += v0.z + v1.z;
    }
    if (j < end) {
        float4 v = wx[recsB[j] & RMASK];
        a0 += v.x; a1 += v.y; a2 += v.z;
    }
    float sc = dinv[nn] / (float)(c > 1 ? c : 1);
    y[nn] = make_float4(a0 * sc, a1 * sc, a2 * sc, 0.0f);
}

// fused: h1 = relu(x@W1+b1 + y@W2); center2 = h1@W1'+b1'; xj2 = dinv * h1@W2'
__global__ __launch_bounds__(256) void k_node12(const float* __restrict__ x,
                                                const float4* __restrict__ y,
                                                const float* __restrict__ c1W1,
                                                const float* __restrict__ c1b1,
                                                const float* __restrict__ c1W2,
                                                const float* __restrict__ c2W1,
                                                const float* __restrict__ c2b1,
                                                const float* __restrict__ c2W2,
                                                const float* __restrict__ dinv,
                                                float* __restrict__ center2,
                                                float* __restrict__ xj2) {
    int nn = blockIdx.x * blockDim.x + threadIdx.x;
    if (nn >= N_NODES) return;
    float x0 = x[nn * 3 + 0], x1 = x[nn * 3 + 1], x2 = x[nn * 3 + 2];
    float4 yy = y[nn];
    float h[F];
#pragma unroll
    for (int k = 0; k < F; ++k) {
        float v = c1b1[k]
                + x0 * c1W1[0 * F + k] + x1 * c1W1[1 * F + k] + x2 * c1W1[2 * F + k]
                + yy.x * c1W2[0 * F + k] + yy.y * c1W2[1 * F + k] + yy.z * c1W2[2 * F + k];
        h[k] = v > 0.0f ? v : 0.0f;
    }
    float di = dinv[nn];
#pragma unroll
    for (int k = 0; k < F; ++k) {
        float c2 = c2b1[k];
        float xx = 0.0f;
#pragma unroll
        for (int i = 0; i < F; ++i) {
            c2 += h[i] * c2W1[i * F + k];
            xx += h[i] * c2W2[i * F + k];
        }
        center2[nn * F + k] = c2;
        xj2[nn * F + k] = di * xx;
    }
}

// conv2 aggregation: 16-lane group per node, lane = feature; register accumulation, no atomics
__global__ __launch_bounds__(256) void k_gather_h(const unsigned* __restrict__ recsB,
                                                  const int* __restrict__ rowptr,
                                                  const int* __restrict__ cnt_in,
                                                  const float* __restrict__ dinv,
                                                  const float* __restrict__ xj2,
                                                  float* __restrict__ s2) {
    int g = threadIdx.x >> 4, k = threadIdx.x & 15;
    int nn = blockIdx.x * 16 + g;
    if (nn >= N_NODES) return;
    int beg = rowptr[nn], c = cnt_in[nn], end = beg + c;
    float acc = 0.0f;
    int j = beg;
    for (; j + 3 < end; j += 4) {
        int r0 = recsB[j] & RMASK, r1 = recsB[j + 1] & RMASK;
        int r2 = recsB[j + 2] & RMASK, r3 = recsB[j + 3] & RMASK;
        float v0 = xj2[r0 * F + k], v1 = xj2[r1 * F + k];
        float v2 = xj2[r2 * F + k], v3 = xj2[r3 * F + k];
        acc += (v0 + v1) + (v2 + v3);
    }
    for (; j < end; ++j) acc += xj2[(recsB[j] & RMASK) * F + k];
    s2[nn * F + k] = acc * dinv[nn] / (float)(c > 1 ? c : 1);
}

// run-length pooling over sorted batch: relu(center2 + s2) summed per graph
__global__ __launch_bounds__(256) void k_pool(const float* __restrict__ center,
                                              const float* __restrict__ s,
                                              const int* __restrict__ batch,
                                              float* __restrict__ gpool,
                                              int* __restrict__ gcnt) {
    int t = blockIdx.x * blockDim.x + threadIdx.x;
    int gid = t >> 4, k = t & 15;
    int n0 = gid * POOL_CHUNK;
    if (n0 >= N_NODES) return;
    int n1 = n0 + POOL_CHUNK; if (n1 > N_NODES) n1 = N_NODES;
    int bcur = batch[n0];
    float acc = 0.0f; int run = 0;
    for (int n = n0; n < n1; ++n) {
        int b = batch[n];
        if (b != bcur) {
            atomicAdd(&gpool[bcur * F + k], acc);
            if (k == 0) atomicAdd(&gcnt[bcur], run);
            acc = 0.0f; run = 0; bcur = b;
        }
        float h = center[n * F + k] + s[n * F + k];
        acc += h > 0.0f ? h : 0.0f;
        ++run;
    }
    atomicAdd(&gpool[bcur * F + k], acc);
    if (k == 0) atomicAdd(&gcnt[bcur], run);
}

__global__ __launch_bounds__(64) void k_mlp(const float* __restrict__ gpool,
                                            const int* __restrict__ gcnt,
                                            const float* __restrict__ l1W,
                                            const float* __restrict__ l1b,
                                            const float* __restrict__ l2W,
                                            const float* __restrict__ l2b,
                                            float* __restrict__ out) {
    int g = threadIdx.x;
    if (g >= N_GRAPHS) return;
    int c = gcnt[g];
    float ic = 1.0f / (float)(c > 1 ? c : 1);
    float v[F], h[F];
#pragma unroll
    for (int k = 0; k < F; ++k) v[k] = gpool[g * F + k] * ic;
#pragma unroll
    for (int k = 0; k < F; ++k) {
        float a = l1b[k];
#pragma unroll
        for (int i = 0; i < F; ++i) a += v[i] * l1W[i * F + k];
        h[k] = a > 0.0f ? a : 0.0f;
    }
#pragma unroll
    for (int j = 0; j < 2; ++j) {
        float a = l2b[j];
#pragma unroll
        for (int i = 0; i < F; ++i) a += h[i] * l2W[i * 2 + j];
        out[g * 2 + j] = a;
    }
}

extern "C" void kernel_launch(void* const* d_in, const int* in_sizes, int n_in,
                              void* d_out, int out_size, void* d_ws, size_t ws_size,
                              hipStream_t stream) {
    const float* x     = (const float*)d_in[0];
    const int*   ei    = (const int*)d_in[1];
    const int*   row   = ei;
    const int*   col   = ei + N_EDGES;
    const int*   batch = (const int*)d_in[2];
    const float* c1W1  = (const float*)d_in[3];
    const float* c1b1  = (const float*)d_in[4];
    const float* c1W2  = (const float*)d_in[5];
    const float* c2W1  = (const float*)d_in[6];
    const float* c2b1  = (const float*)d_in[7];
    const float* c2W2  = (const float*)d_in[8];
    const float* l1W   = (const float*)d_in[9];
    const float* l1b   = (const float*)d_in[10];
    const float* l2W   = (const float*)d_in[11];
    const float* l2b   = (const float*)d_in[12];
    float* out = (float*)d_out;

    char* p = (char*)d_ws;
    auto alloc = [&p](size_t bytes) -> void* {
        void* r = (void*)p;
        p += (bytes + 255) & ~(size_t)255;
        return r;
    };
    float*          dinv    = (float*)         alloc(N_NODES * 4);
    float4*         wx      = (float4*)        alloc((size_t)N_NODES * 16);
    float4*         y       = (float4*)        alloc((size_t)N_NODES * 16);
    float*          center2 = (float*)         alloc((size_t)N_NODES * F * 4);
    float*          xj2     = (float*)         alloc((size_t)N_NODES * F * 4);
    float*          s2      = (float*)         alloc((size_t)N_NODES * F * 4);
    float*          gpool   = (float*)         alloc(N_GRAPHS * F * 4);
    int*            gcnt    = (int*)           alloc(N_GRAPHS * 4);
    int*            bhistC  = (int*)           alloc(NBUCK * 4);
    int*            bhistR  = (int*)           alloc(NBUCK * 4);
    int*            bbaseC  = (int*)           alloc((NBUCK + 1) * 4);
    int*            bbaseR  = (int*)           alloc((NBUCK + 1) * 4);
    int*            cntmatC = (int*)           alloc((size_t)NBUCK * NBLK * 4);
    int*            cntmatR = (int*)           alloc((size_t)NBUCK * NBLK * 4);
    int*            rowptr  = (int*)           alloc((size_t)N_NODES * 4);
    int*            cnt_in  = (int*)           alloc((size_t)N_NODES * 4);
    unsigned*       recsA   = (unsigned*)      alloc(((size_t)N_EDGES + NBUCK * 16) * 4);
    unsigned*       recsB   = (unsigned*)      alloc(((size_t)N_EDGES + NBUCK * 16) * 4);
    unsigned short* rrecs   = (unsigned short*)alloc(((size_t)N_EDGES + NBUCK * 16) * 2);

    hipMemsetAsync(gpool, 0, N_GRAPHS * F * 4, stream);
    hipMemsetAsync(gcnt, 0, N_GRAPHS * 4, stream);

    k_histAB<<<NBLK, 256, 0, stream>>>(row, col, cntmatC, cntmatR);
    k_colscan2<<<2 * NBUCK, 256, 0, stream>>>(cntmatC, cntmatR, bhistC, bhistR);
    k_bscan2<<<2, 256, 0, stream>>>(bhistC, bhistR, bbaseC, bbaseR);
    k_fill3<<<NBLK, 256, 0, stream>>>(row, col, cntmatC, cntmatR, bbaseC, bbaseR, recsA, rrecs);
    k_deg391<<<NBUCK, 256, 0, stream>>>(rrecs, bbaseR, bhistR, x, dinv, wx);
    k_sort391<<<NBUCK, 256, 0, stream>>>(recsA, bbaseC, bhistC, recsB, rowptr, cnt_in);

    k_gather_x<<<(N_NODES + 255) / 256, 256, 0, stream>>>(recsB, rowptr, cnt_in, dinv, wx, y);
    k_node12<<<(N_NODES + 255) / 256, 256, 0, stream>>>(x, y, c1W1, c1b1, c1W2,
                                                        c2W1, c2b1, c2W2, dinv, center2, xj2);
    k_gather_h<<<(N_NODES + 15) / 16, 256, 0, stream>>>(recsB, rowptr, cnt_in, dinv, xj2, s2);

    k_pool<<<((N_NODES + POOL_CHUNK - 1) / POOL_CHUNK * 16 + 255) / 256, 256, 0, stream>>>(
        center2, s2, batch, gpool, gcnt);
    k_mlp<<<1, 64, 0, stream>>>(gpool, gcnt, l1W, l1b, l2W, l2b, out);
}

// Round 9
// 216.702 us; speedup vs baseline: 3.7718x; 1.1433x over previous
//
#include <hip/hip_runtime.h>

#define N_NODES 100000
#define N_EDGES 3200000
#define N_GRAPHS 64
#define F 16

#define NBUCK 256
#define CPB 391                 // cols per bucket: 256*391 = 100096 >= N_NODES
#define NBLK 256                // sort blocks (fewer -> longer dense segments)
#define EPB ((N_EDGES + NBLK - 1) / NBLK)   // 12500 edges per block
#define RMASK 0x1FFFF
#define PCHUNK 64               // nodes per gpool block

// Pass 1: per-block LDS histograms of BOTH col-buckets and row-buckets (no global atomics)
__global__ __launch_bounds__(256) void k_histAB(const int* __restrict__ row,
                                                const int* __restrict__ col,
                                                int* __restrict__ cntmatC,
                                                int* __restrict__ cntmatR) {
    __shared__ int lhc[NBUCK], lhr[NBUCK];
    for (int i = threadIdx.x; i < NBUCK; i += 256) { lhc[i] = 0; lhr[i] = 0; }
    __syncthreads();
    int beg = blockIdx.x * EPB;
    int end = beg + EPB; if (end > N_EDGES) end = N_EDGES;
    for (int e = beg + threadIdx.x; e < end; e += 256) {
        atomicAdd(&lhc[(unsigned)col[e] / CPB], 1);
        atomicAdd(&lhr[(unsigned)row[e] / CPB], 1);
    }
    __syncthreads();
    for (int i = threadIdx.x; i < NBUCK; i += 256) {
        cntmatC[i * NBLK + blockIdx.x] = lhc[i];
        cntmatR[i * NBLK + blockIdx.x] = lhr[i];
    }
}

// Pass 2: per-bucket exclusive scan across 256 blocks (grid 0-255: col, 256-511: row)
__global__ __launch_bounds__(256) void k_colscan2(int* __restrict__ cntmatC,
                                                  int* __restrict__ cntmatR,
                                                  int* __restrict__ bhistC,
                                                  int* __restrict__ bhistR) {
    __shared__ int sd[256];
    int which = blockIdx.x >> 8;
    int b = blockIdx.x & 255, t = threadIdx.x;
    int* cm = which ? cntmatR : cntmatC;
    int* bh = which ? bhistR : bhistC;
    int v = cm[b * NBLK + t];
    sd[t] = v;
    __syncthreads();
    for (int off = 1; off < 256; off <<= 1) {
        int a = (t >= off) ? sd[t - off] : 0;
        __syncthreads();
        sd[t] += a;
        __syncthreads();
    }
    cm[b * NBLK + t] = sd[t] - v;
    if (t == 255) bh[b] = sd[255];
}

// Pass 3: exclusive scan of 16-padded bucket totals (block 0: col, block 1: row)
__global__ __launch_bounds__(256) void k_bscan2(const int* __restrict__ bhistC,
                                                const int* __restrict__ bhistR,
                                                int* __restrict__ bbaseC,
                                                int* __restrict__ bbaseR) {
    __shared__ int sd[NBUCK];
    const int* h = blockIdx.x == 0 ? bhistC : bhistR;
    int* o = blockIdx.x == 0 ? bbaseC : bbaseR;
    int t = threadIdx.x;
    int v = (h[t] + 15) & ~15;
    sd[t] = v;
    __syncthreads();
    for (int off = 1; off < NBUCK; off <<= 1) {
        int a = (t >= off) ? sd[t - off] : 0;
        __syncthreads();
        sd[t] += a;
        __syncthreads();
    }
    o[t] = sd[t] - v;
}

// Pass 4: dual deterministic scatter: col-grouped recsA + row-bucket-grouped rrecs tokens
__global__ __launch_bounds__(256) void k_fill3(const int* __restrict__ row,
                                               const int* __restrict__ col,
                                               const int* __restrict__ cntmatC,
                                               const int* __restrict__ cntmatR,
                                               const int* __restrict__ bbaseC,
                                               const int* __restrict__ bbaseR,
                                               unsigned* __restrict__ recsA,
                                               unsigned short* __restrict__ rrecs) {
    __shared__ int ptrC[NBUCK], ptrR[NBUCK];
    for (int i = threadIdx.x; i < NBUCK; i += 256) {
        ptrC[i] = bbaseC[i] + cntmatC[i * NBLK + blockIdx.x];
        ptrR[i] = bbaseR[i] + cntmatR[i * NBLK + blockIdx.x];
    }
    __syncthreads();
    int beg = blockIdx.x * EPB;
    int end = beg + EPB; if (end > N_EDGES) end = N_EDGES;
    for (int e = beg + threadIdx.x; e < end; e += 256) {
        unsigned c = (unsigned)col[e];
        unsigned r = (unsigned)row[e];
        unsigned bc = c / CPB;
        int slot = atomicAdd(&ptrC[bc], 1);
        recsA[slot] = ((c - bc * CPB) << 17) | r;
        unsigned br = r / CPB;
        int slotR = atomicAdd(&ptrR[br], 1);
        rrecs[slotR] = (unsigned short)(r - br * CPB);
    }
}

// Pass 5 (merged): blocks 0-255: per-col-bucket counting sort -> recsB + rowptr + cnt_in
//                  blocks 256-511: per-row-bucket degree histogram -> dinv + wx
__global__ __launch_bounds__(256) void k_degsort(const unsigned* __restrict__ recsA,
                                                 const int* __restrict__ bbaseC,
                                                 const int* __restrict__ bhistC,
                                                 unsigned* __restrict__ recsB,
                                                 int* __restrict__ rowptr,
                                                 int* __restrict__ cnt_in,
                                                 const unsigned short* __restrict__ rrecs,
                                                 const int* __restrict__ bbaseR,
                                                 const int* __restrict__ bhistR,
                                                 const float* __restrict__ x,
                                                 float* __restrict__ dinv,
                                                 float4* __restrict__ wx) {
    __shared__ int hist[CPB];
    __shared__ int scn[512];
    __shared__ int off[CPB];
    int t = threadIdx.x;
    if (blockIdx.x < NBUCK) {
        int b = blockIdx.x;
        for (int i = t; i < CPB; i += 256) hist[i] = 0;
        __syncthreads();
        int beg = bbaseC[b], n = bhistC[b];
        for (int i = t; i < n; i += 256)
            atomicAdd(&hist[recsA[beg + i] >> 17], 1);
        __syncthreads();
        scn[t]       = (t < CPB) ? hist[t] : 0;
        scn[t + 256] = (t + 256 < CPB) ? hist[t + 256] : 0;
        __syncthreads();
        for (int o = 1; o < 512; o <<= 1) {
            int v0 = (t >= o) ? scn[t - o] : 0;
            int v1 = (t + 256 >= o) ? scn[t + 256 - o] : 0;
            __syncthreads();
            scn[t] += v0; scn[t + 256] += v1;
            __syncthreads();
        }
        for (int lc = t; lc < CPB; lc += 256) {
            int ex = scn[lc] - hist[lc];
            off[lc] = ex;
            int node = b * CPB + lc;
            if (node < N_NODES) { rowptr[node] = beg + ex; cnt_in[node] = hist[lc]; }
        }
        __syncthreads();
        for (int i = t; i < n; i += 256) {
            unsigned rec = recsA[beg + i];
            int d = atomicAdd(&off[rec >> 17], 1);
            recsB[beg + d] = rec;
        }
    } else {
        int b = blockIdx.x - NBUCK;
        for (int i = t; i < CPB; i += 256) hist[i] = 0;
        __syncthreads();
        int beg = bbaseR[b], n = bhistR[b];
        for (int i = t; i < n; i += 256)
            atomicAdd(&hist[rrecs[beg + i]], 1);
        __syncthreads();
        for (int lc = t; lc < CPB; lc += 256) {
            int node = b * CPB + lc;
            if (node >= N_NODES) continue;
            int d = hist[lc];
            float di = d > 0 ? rsqrtf((float)d) : 0.0f;
            dinv[node] = di;
            wx[node] = make_float4(di * x[node * 3 + 0], di * x[node * 3 + 1],
                                   di * x[node * 3 + 2], 0.0f);
        }
    }
}

// Fused conv1: y = gather(wx) (3 feats), h1 = relu(x@W1+b1 + y@W2),
// center2 = h1@W1'+b1', xj2 = dinv * h1@W2'
__global__ __launch_bounds__(256) void k_conv1(const unsigned* __restrict__ recsB,
                                               const int* __restrict__ rowptr,
                                               const int* __restrict__ cnt_in,
                                               const float* __restrict__ dinv,
                                               const float4* __restrict__ wx,
                                               const float* __restrict__ x,
                                               const float* __restrict__ c1W1,
                                               const float* __restrict__ c1b1,
                                               const float* __restrict__ c1W2,
                                               const float* __restrict__ c2W1,
                                               const float* __restrict__ c2b1,
                                               const float* __restrict__ c2W2,
                                               float* __restrict__ center2,
                                               float* __restrict__ xj2) {
    int nn = blockIdx.x * blockDim.x + threadIdx.x;
    if (nn >= N_NODES) return;
    int beg = rowptr[nn], c = cnt_in[nn], end = beg + c;
    float a0 = 0.0f, a1 = 0.0f, a2 = 0.0f;
    int j = beg;
    for (; j + 1 < end; j += 2) {
        int r0 = recsB[j] & RMASK, r1 = recsB[j + 1] & RMASK;
        float4 v0 = wx[r0], v1 = wx[r1];
        a0 += v0.x + v1.x; a1 += v0.y + v1.y; a2 += v0.z + v1.z;
    }
    if (j < end) {
        float4 v = wx[recsB[j] & RMASK];
        a0 += v.x; a1 += v.y; a2 += v.z;
    }
    float sc = dinv[nn] / (float)(c > 1 ? c : 1);
    float y0 = a0 * sc, y1 = a1 * sc, y2 = a2 * sc;
    float x0 = x[nn * 3 + 0], x1 = x[nn * 3 + 1], x2 = x[nn * 3 + 2];
    float h[F];
#pragma unroll
    for (int k = 0; k < F; ++k) {
        float v = c1b1[k]
                + x0 * c1W1[0 * F + k] + x1 * c1W1[1 * F + k] + x2 * c1W1[2 * F + k]
                + y0 * c1W2[0 * F + k] + y1 * c1W2[1 * F + k] + y2 * c1W2[2 * F + k];
        h[k] = v > 0.0f ? v : 0.0f;
    }
    float di = dinv[nn];
#pragma unroll
    for (int k = 0; k < F; ++k) {
        float c2 = c2b1[k];
        float xx = 0.0f;
#pragma unroll
        for (int i = 0; i < F; ++i) {
            c2 += h[i] * c2W1[i * F + k];
            xx += h[i] * c2W2[i * F + k];
        }
        center2[nn * F + k] = c2;
        xj2[nn * F + k] = di * xx;
    }
}

// Fused conv2-aggregation + pooling: 1024 threads = 64 nodes x 16 feature-lanes.
// s2 stays in registers; relu(center2+s2) pooled via run-length over sorted batch.
__global__ __launch_bounds__(1024) void k_gpool(const unsigned* __restrict__ recsB,
                                                const int* __restrict__ rowptr,
                                                const int* __restrict__ cnt_in,
                                                const float* __restrict__ dinv,
                                                const float* __restrict__ xj2,
                                                const float* __restrict__ center2,
                                                const int* __restrict__ batch,
                                                float* __restrict__ gpool,
                                                int* __restrict__ gcnt) {
    __shared__ float tile[PCHUNK][F + 1];
    __shared__ int bid[PCHUNK];
    int g = threadIdx.x >> 4, k = threadIdx.x & 15;
    int nn = blockIdx.x * PCHUNK + g;
    bool valid = nn < N_NODES;
    float hval = 0.0f;
    if (valid) {
        int beg = rowptr[nn], c = cnt_in[nn], end = beg + c;
        float acc = 0.0f;
        int j = beg;
        for (; j + 3 < end; j += 4) {
            int r0 = recsB[j] & RMASK, r1 = recsB[j + 1] & RMASK;
            int r2 = recsB[j + 2] & RMASK, r3 = recsB[j + 3] & RMASK;
            float v0 = xj2[r0 * F + k], v1 = xj2[r1 * F + k];
            float v2 = xj2[r2 * F + k], v3 = xj2[r3 * F + k];
            acc += (v0 + v1) + (v2 + v3);
        }
        for (; j < end; ++j) acc += xj2[(recsB[j] & RMASK) * F + k];
        float s2 = acc * dinv[nn] / (float)(c > 1 ? c : 1);
        hval = center2[nn * F + k] + s2;
        hval = hval > 0.0f ? hval : 0.0f;
        if (k == 0) bid[g] = batch[nn];
    } else if (k == 0) {
        bid[g] = -1;
    }
    tile[g][k] = hval;
    __syncthreads();
    if (threadIdx.x < 16) {
        int kk = threadIdx.x;
        int bcur = -2; float acc = 0.0f; int run = 0;
        for (int gg = 0; gg < PCHUNK; ++gg) {
            int b = bid[gg];
            if (b < 0) break;   // tail: invalid nodes only at the end
            if (b != bcur) {
                if (bcur >= 0) {
                    atomicAdd(&gpool[bcur * F + kk], acc);
                    if (kk == 0) atomicAdd(&gcnt[bcur], run);
                }
                acc = 0.0f; run = 0; bcur = b;
            }
            acc += tile[gg][kk];
            ++run;
        }
        if (bcur >= 0) {
            atomicAdd(&gpool[bcur * F + kk], acc);
            if (kk == 0) atomicAdd(&gcnt[bcur], run);
        }
    }
}

__global__ __launch_bounds__(64) void k_mlp(const float* __restrict__ gpool,
                                            const int* __restrict__ gcnt,
                                            const float* __restrict__ l1W,
                                            const float* __restrict__ l1b,
                                            const float* __restrict__ l2W,
                                            const float* __restrict__ l2b,
                                            float* __restrict__ out) {
    int g = threadIdx.x;
    if (g >= N_GRAPHS) return;
    int c = gcnt[g];
    float ic = 1.0f / (float)(c > 1 ? c : 1);
    float v[F], h[F];
#pragma unroll
    for (int k = 0; k < F; ++k) v[k] = gpool[g * F + k] * ic;
#pragma unroll
    for (int k = 0; k < F; ++k) {
        float a = l1b[k];
#pragma unroll
        for (int i = 0; i < F; ++i) a += v[i] * l1W[i * F + k];
        h[k] = a > 0.0f ? a : 0.0f;
    }
#pragma unroll
    for (int j = 0; j < 2; ++j) {
        float a = l2b[j];
#pragma unroll
        for (int i = 0; i < F; ++i) a += h[i] * l2W[i * 2 + j];
        out[g * 2 + j] = a;
    }
}

extern "C" void kernel_launch(void* const* d_in, const int* in_sizes, int n_in,
                              void* d_out, int out_size, void* d_ws, size_t ws_size,
                              hipStream_t stream) {
    const float* x     = (const float*)d_in[0];
    const int*   ei    = (const int*)d_in[1];
    const int*   row   = ei;
    const int*   col   = ei + N_EDGES;
    const int*   batch = (const int*)d_in[2];
    const float* c1W1  = (const float*)d_in[3];
    const float* c1b1  = (const float*)d_in[4];
    const float* c1W2  = (const float*)d_in[5];
    const float* c2W1  = (const float*)d_in[6];
    const float* c2b1  = (const float*)d_in[7];
    const float* c2W2  = (const float*)d_in[8];
    const float* l1W   = (const float*)d_in[9];
    const float* l1b   = (const float*)d_in[10];
    const float* l2W   = (const float*)d_in[11];
    const float* l2b   = (const float*)d_in[12];
    float* out = (float*)d_out;

    char* p = (char*)d_ws;
    auto alloc = [&p](size_t bytes) -> void* {
        void* r = (void*)p;
        p += (bytes + 255) & ~(size_t)255;
        return r;
    };
    float*          dinv    = (float*)         alloc(N_NODES * 4);
    float4*         wx      = (float4*)        alloc((size_t)N_NODES * 16);
    float*          center2 = (float*)         alloc((size_t)N_NODES * F * 4);
    float*          xj2     = (float*)         alloc((size_t)N_NODES * F * 4);
    float*          gpool   = (float*)         alloc(N_GRAPHS * F * 4);
    int*            gcnt    = (int*)           alloc(N_GRAPHS * 4);
    int*            bhistC  = (int*)           alloc(NBUCK * 4);
    int*            bhistR  = (int*)           alloc(NBUCK * 4);
    int*            bbaseC  = (int*)           alloc((NBUCK + 1) * 4);
    int*            bbaseR  = (int*)           alloc((NBUCK + 1) * 4);
    int*            cntmatC = (int*)           alloc((size_t)NBUCK * NBLK * 4);
    int*            cntmatR = (int*)           alloc((size_t)NBUCK * NBLK * 4);
    int*            rowptr  = (int*)           alloc((size_t)N_NODES * 4);
    int*            cnt_in  = (int*)           alloc((size_t)N_NODES * 4);
    unsigned*       recsA   = (unsigned*)      alloc(((size_t)N_EDGES + NBUCK * 16) * 4);
    unsigned*       recsB   = (unsigned*)      alloc(((size_t)N_EDGES + NBUCK * 16) * 4);
    unsigned short* rrecs   = (unsigned short*)alloc(((size_t)N_EDGES + NBUCK * 16) * 2);

    hipMemsetAsync(gpool, 0, N_GRAPHS * F * 4, stream);
    hipMemsetAsync(gcnt, 0, N_GRAPHS * 4, stream);

    k_histAB<<<NBLK, 256, 0, stream>>>(row, col, cntmatC, cntmatR);
    k_colscan2<<<2 * NBUCK, 256, 0, stream>>>(cntmatC, cntmatR, bhistC, bhistR);
    k_bscan2<<<2, 256, 0, stream>>>(bhistC, bhistR, bbaseC, bbaseR);
    k_fill3<<<NBLK, 256, 0, stream>>>(row, col, cntmatC, cntmatR, bbaseC, bbaseR, recsA, rrecs);
    k_degsort<<<2 * NBUCK, 256, 0, stream>>>(recsA, bbaseC, bhistC, recsB, rowptr, cnt_in,
                                             rrecs, bbaseR, bhistR, x, dinv, wx);
    k_conv1<<<(N_NODES + 255) / 256, 256, 0, stream>>>(recsB, rowptr, cnt_in, dinv, wx, x,
                                                       c1W1, c1b1, c1W2, c2W1, c2b1, c2W2,
                                                       center2, xj2);
    k_gpool<<<(N_NODES + PCHUNK - 1) / PCHUNK, 1024, 0, stream>>>(
        recsB, rowptr, cnt_in, dinv, xj2, center2, batch, gpool, gcnt);
    k_mlp<<<1, 64, 0, stream>>>(gpool, gcnt, l1W, l1b, l2W, l2b, out);
}

// Round 10
// 207.923 us; speedup vs baseline: 3.9311x; 1.0422x over previous
//
#include <hip/hip_runtime.h>
#include <hip/hip_fp16.h>

#define N_NODES 100000
#define N_EDGES 3200000
#define N_GRAPHS 64
#define F 16

#define NBUCK 256
#define CPB 391                 // cols per bucket: 256*391 = 100096 >= N_NODES
#define NBLK 256                // sort blocks
#define EPB ((N_EDGES + NBLK - 1) / NBLK)   // 12500 edges per block
#define RMASK 0x1FFFF
#define PCHUNK 64               // nodes per gpool block

// Pass 1: per-block LDS histograms of col-buckets and row-buckets; bucket totals via
// integer atomics (deterministic) so the bbase scan can run concurrently with cnt scans.
__global__ __launch_bounds__(256) void k_histAB(const int* __restrict__ row,
                                                const int* __restrict__ col,
                                                int* __restrict__ cntmatC,
                                                int* __restrict__ cntmatR,
                                                int* __restrict__ bhistC,
                                                int* __restrict__ bhistR) {
    __shared__ int lhc[NBUCK], lhr[NBUCK];
    for (int i = threadIdx.x; i < NBUCK; i += 256) { lhc[i] = 0; lhr[i] = 0; }
    __syncthreads();
    int beg = blockIdx.x * EPB;
    int end = beg + EPB; if (end > N_EDGES) end = N_EDGES;
    for (int e = beg + threadIdx.x; e < end; e += 256) {
        atomicAdd(&lhc[(unsigned)col[e] / CPB], 1);
        atomicAdd(&lhr[(unsigned)row[e] / CPB], 1);
    }
    __syncthreads();
    for (int i = threadIdx.x; i < NBUCK; i += 256) {
        int c = lhc[i], r = lhr[i];
        cntmatC[i * NBLK + blockIdx.x] = c;
        cntmatR[i * NBLK + blockIdx.x] = r;
        if (c) atomicAdd(&bhistC[i], c);
        if (r) atomicAdd(&bhistR[i], r);
    }
}

// Pass 2 (merged): blocks 0-255 scan cntmatC rows, 256-511 scan cntmatR rows,
// block 512/513: exclusive scan of 16-padded bucket totals -> bbaseC/bbaseR.
__global__ __launch_bounds__(256) void k_scans(int* __restrict__ cntmatC,
                                               int* __restrict__ cntmatR,
                                               const int* __restrict__ bhistC,
                                               const int* __restrict__ bhistR,
                                               int* __restrict__ bbaseC,
                                               int* __restrict__ bbaseR) {
    __shared__ int sd[256];
    int t = threadIdx.x;
    if (blockIdx.x < 2 * NBUCK) {
        int which = blockIdx.x >> 8;
        int b = blockIdx.x & 255;
        int* cm = which ? cntmatR : cntmatC;
        int v = cm[b * NBLK + t];
        sd[t] = v;
        __syncthreads();
        for (int off = 1; off < 256; off <<= 1) {
            int a = (t >= off) ? sd[t - off] : 0;
            __syncthreads();
            sd[t] += a;
            __syncthreads();
        }
        cm[b * NBLK + t] = sd[t] - v;
    } else {
        const int* h = (blockIdx.x == 2 * NBUCK) ? bhistC : bhistR;
        int* o = (blockIdx.x == 2 * NBUCK) ? bbaseC : bbaseR;
        int v = (h[t] + 15) & ~15;
        sd[t] = v;
        __syncthreads();
        for (int off = 1; off < NBUCK; off <<= 1) {
            int a = (t >= off) ? sd[t - off] : 0;
            __syncthreads();
            sd[t] += a;
            __syncthreads();
        }
        o[t] = sd[t] - v;
    }
}

// Pass 3: dual deterministic scatter: col-grouped recsA + row-bucket-grouped rrecs tokens
__global__ __launch_bounds__(256) void k_fill3(const int* __restrict__ row,
                                               const int* __restrict__ col,
                                               const int* __restrict__ cntmatC,
                                               const int* __restrict__ cntmatR,
                                               const int* __restrict__ bbaseC,
                                               const int* __restrict__ bbaseR,
                                               unsigned* __restrict__ recsA,
                                               unsigned short* __restrict__ rrecs) {
    __shared__ int ptrC[NBUCK], ptrR[NBUCK];
    for (int i = threadIdx.x; i < NBUCK; i += 256) {
        ptrC[i] = bbaseC[i] + cntmatC[i * NBLK + blockIdx.x];
        ptrR[i] = bbaseR[i] + cntmatR[i * NBLK + blockIdx.x];
    }
    __syncthreads();
    int beg = blockIdx.x * EPB;
    int end = beg + EPB; if (end > N_EDGES) end = N_EDGES;
    for (int e = beg + threadIdx.x; e < end; e += 256) {
        unsigned c = (unsigned)col[e];
        unsigned r = (unsigned)row[e];
        unsigned bc = c / CPB;
        int slot = atomicAdd(&ptrC[bc], 1);
        recsA[slot] = ((c - bc * CPB) << 17) | r;
        unsigned br = r / CPB;
        int slotR = atomicAdd(&ptrR[br], 1);
        rrecs[slotR] = (unsigned short)(r - br * CPB);
    }
}

// Pass 4 (merged): blocks 0-255: per-col-bucket counting sort -> recsB + rowptr + cnt_in
//                  blocks 256-511: per-row-bucket degree histogram -> dinv + wx
__global__ __launch_bounds__(256) void k_degsort(const unsigned* __restrict__ recsA,
                                                 const int* __restrict__ bbaseC,
                                                 const int* __restrict__ bhistC,
                                                 unsigned* __restrict__ recsB,
                                                 int* __restrict__ rowptr,
                                                 int* __restrict__ cnt_in,
                                                 const unsigned short* __restrict__ rrecs,
                                                 const int* __restrict__ bbaseR,
                                                 const int* __restrict__ bhistR,
                                                 const float* __restrict__ x,
                                                 float* __restrict__ dinv,
                                                 float4* __restrict__ wx) {
    __shared__ int hist[CPB];
    __shared__ int scn[512];
    __shared__ int off[CPB];
    int t = threadIdx.x;
    if (blockIdx.x < NBUCK) {
        int b = blockIdx.x;
        for (int i = t; i < CPB; i += 256) hist[i] = 0;
        __syncthreads();
        int beg = bbaseC[b], n = bhistC[b];
        for (int i = t; i < n; i += 256)
            atomicAdd(&hist[recsA[beg + i] >> 17], 1);
        __syncthreads();
        scn[t]       = (t < CPB) ? hist[t] : 0;
        scn[t + 256] = (t + 256 < CPB) ? hist[t + 256] : 0;
        __syncthreads();
        for (int o = 1; o < 512; o <<= 1) {
            int v0 = (t >= o) ? scn[t - o] : 0;
            int v1 = (t + 256 >= o) ? scn[t + 256 - o] : 0;
            __syncthreads();
            scn[t] += v0; scn[t + 256] += v1;
            __syncthreads();
        }
        for (int lc = t; lc < CPB; lc += 256) {
            int ex = scn[lc] - hist[lc];
            off[lc] = ex;
            int node = b * CPB + lc;
            if (node < N_NODES) { rowptr[node] = beg + ex; cnt_in[node] = hist[lc]; }
        }
        __syncthreads();
        for (int i = t; i < n; i += 256) {
            unsigned rec = recsA[beg + i];
            int d = atomicAdd(&off[rec >> 17], 1);
            recsB[beg + d] = rec;
        }
    } else {
        int b = blockIdx.x - NBUCK;
        for (int i = t; i < CPB; i += 256) hist[i] = 0;
        __syncthreads();
        int beg = bbaseR[b], n = bhistR[b];
        for (int i = t; i < n; i += 256)
            atomicAdd(&hist[rrecs[beg + i]], 1);
        __syncthreads();
        for (int lc = t; lc < CPB; lc += 256) {
            int node = b * CPB + lc;
            if (node >= N_NODES) continue;
            int d = hist[lc];
            float di = d > 0 ? rsqrtf((float)d) : 0.0f;
            dinv[node] = di;
            wx[node] = make_float4(di * x[node * 3 + 0], di * x[node * 3 + 1],
                                   di * x[node * 3 + 2], 0.0f);
        }
    }
}

// Fused conv1: y = gather(wx) (3 feats), h1 = relu(x@W1+b1 + y@W2),
// center2 = h1@W1'+b1' (fp32), xj2 = dinv * h1@W2' stored FP16 (3.2MB -> L2-resident)
__global__ __launch_bounds__(256) void k_conv1(const unsigned* __restrict__ recsB,
                                               const int* __restrict__ rowptr,
                                               const int* __restrict__ cnt_in,
                                               const float* __restrict__ dinv,
                                               const float4* __restrict__ wx,
                                               const float* __restrict__ x,
                                               const float* __restrict__ c1W1,
                                               const float* __restrict__ c1b1,
                                               const float* __restrict__ c1W2,
                                               const float* __restrict__ c2W1,
                                               const float* __restrict__ c2b1,
                                               const float* __restrict__ c2W2,
                                               float* __restrict__ center2,
                                               __half* __restrict__ xj2h) {
    int nn = blockIdx.x * blockDim.x + threadIdx.x;
    if (nn >= N_NODES) return;
    int beg = rowptr[nn], c = cnt_in[nn], end = beg + c;
    float a0 = 0.0f, a1 = 0.0f, a2 = 0.0f;
    int j = beg;
    for (; j + 1 < end; j += 2) {
        int r0 = recsB[j] & RMASK, r1 = recsB[j + 1] & RMASK;
        float4 v0 = wx[r0], v1 = wx[r1];
        a0 += v0.x + v1.x; a1 += v0.y + v1.y; a2 += v0.z + v1.z;
    }
    if (j < end) {
        float4 v = wx[recsB[j] & RMASK];
        a0 += v.x; a1 += v.y; a2 += v.z;
    }
    float sc = dinv[nn] / (float)(c > 1 ? c : 1);
    float y0 = a0 * sc, y1 = a1 * sc, y2 = a2 * sc;
    float x0 = x[nn * 3 + 0], x1 = x[nn * 3 + 1], x2 = x[nn * 3 + 2];
    float h[F];
#pragma unroll
    for (int k = 0; k < F; ++k) {
        float v = c1b1[k]
                + x0 * c1W1[0 * F + k] + x1 * c1W1[1 * F + k] + x2 * c1W1[2 * F + k]
                + y0 * c1W2[0 * F + k] + y1 * c1W2[1 * F + k] + y2 * c1W2[2 * F + k];
        h[k] = v > 0.0f ? v : 0.0f;
    }
    float di = dinv[nn];
    float cc[F];
    union { __half hh[F]; uint4 v4[2]; } u;
#pragma unroll
    for (int k = 0; k < F; ++k) {
        float c2 = c2b1[k];
        float xx = 0.0f;
#pragma unroll
        for (int i = 0; i < F; ++i) {
            c2 += h[i] * c2W1[i * F + k];
            xx += h[i] * c2W2[i * F + k];
        }
        cc[k] = c2;
        u.hh[k] = __float2half_rn(di * xx);
    }
    float4* cd = (float4*)(center2 + nn * F);
#pragma unroll
    for (int q = 0; q < 4; ++q)
        cd[q] = make_float4(cc[q * 4 + 0], cc[q * 4 + 1], cc[q * 4 + 2], cc[q * 4 + 3]);
    uint4* xd = (uint4*)(xj2h + nn * F);
    xd[0] = u.v4[0];
    xd[1] = u.v4[1];
}

// Fused conv2-aggregation + pooling: 1024 threads = 64 nodes x 16 feature-lanes.
// xj2 reads are fp16 (L2-resident); s2 stays in registers; run-length pooled.
__global__ __launch_bounds__(1024) void k_gpool(const unsigned* __restrict__ recsB,
                                                const int* __restrict__ rowptr,
                                                const int* __restrict__ cnt_in,
                                                const float* __restrict__ dinv,
                                                const __half* __restrict__ xj2h,
                                                const float* __restrict__ center2,
                                                const int* __restrict__ batch,
                                                float* __restrict__ gpool,
                                                int* __restrict__ gcnt) {
    __shared__ float tile[PCHUNK][F + 1];
    __shared__ int bid[PCHUNK];
    int g = threadIdx.x >> 4, k = threadIdx.x & 15;
    int nn = blockIdx.x * PCHUNK + g;
    bool valid = nn < N_NODES;
    float hval = 0.0f;
    if (valid) {
        int beg = rowptr[nn], c = cnt_in[nn], end = beg + c;
        float acc = 0.0f;
        int j = beg;
        for (; j + 3 < end; j += 4) {
            int r0 = recsB[j] & RMASK, r1 = recsB[j + 1] & RMASK;
            int r2 = recsB[j + 2] & RMASK, r3 = recsB[j + 3] & RMASK;
            float v0 = __half2float(xj2h[r0 * F + k]);
            float v1 = __half2float(xj2h[r1 * F + k]);
            float v2 = __half2float(xj2h[r2 * F + k]);
            float v3 = __half2float(xj2h[r3 * F + k]);
            acc += (v0 + v1) + (v2 + v3);
        }
        for (; j < end; ++j) acc += __half2float(xj2h[(recsB[j] & RMASK) * F + k]);
        float s2 = acc * dinv[nn] / (float)(c > 1 ? c : 1);
        hval = center2[nn * F + k] + s2;
        hval = hval > 0.0f ? hval : 0.0f;
        if (k == 0) bid[g] = batch[nn];
    } else if (k == 0) {
        bid[g] = -1;
    }
    tile[g][k] = hval;
    __syncthreads();
    if (threadIdx.x < 16) {
        int kk = threadIdx.x;
        int bcur = -2; float acc = 0.0f; int run = 0;
        for (int gg = 0; gg < PCHUNK; ++gg) {
            int b = bid[gg];
            if (b < 0) break;   // tail: invalid nodes only at the end
            if (b != bcur) {
                if (bcur >= 0) {
                    atomicAdd(&gpool[bcur * F + kk], acc);
                    if (kk == 0) atomicAdd(&gcnt[bcur], run);
                }
                acc = 0.0f; run = 0; bcur = b;
            }
            acc += tile[gg][kk];
            ++run;
        }
        if (bcur >= 0) {
            atomicAdd(&gpool[bcur * F + kk], acc);
            if (kk == 0) atomicAdd(&gcnt[bcur], run);
        }
    }
}

__global__ __launch_bounds__(64) void k_mlp(const float* __restrict__ gpool,
                                            const int* __restrict__ gcnt,
                                            const float* __restrict__ l1W,
                                            const float* __restrict__ l1b,
                                            const float* __restrict__ l2W,
                                            const float* __restrict__ l2b,
                                            float* __restrict__ out) {
    int g = threadIdx.x;
    if (g >= N_GRAPHS) return;
    int c = gcnt[g];
    float ic = 1.0f / (float)(c > 1 ? c : 1);
    float v[F], h[F];
#pragma unroll
    for (int k = 0; k < F; ++k) v[k] = gpool[g * F + k] * ic;
#pragma unroll
    for (int k = 0; k < F; ++k) {
        float a = l1b[k];
#pragma unroll
        for (int i = 0; i < F; ++i) a += v[i] * l1W[i * F + k];
        h[k] = a > 0.0f ? a : 0.0f;
    }
#pragma unroll
    for (int j = 0; j < 2; ++j) {
        float a = l2b[j];
#pragma unroll
        for (int i = 0; i < F; ++i) a += h[i] * l2W[i * 2 + j];
        out[g * 2 + j] = a;
    }
}

extern "C" void kernel_launch(void* const* d_in, const int* in_sizes, int n_in,
                              void* d_out, int out_size, void* d_ws, size_t ws_size,
                              hipStream_t stream) {
    const float* x     = (const float*)d_in[0];
    const int*   ei    = (const int*)d_in[1];
    const int*   row   = ei;
    const int*   col   = ei + N_EDGES;
    const int*   batch = (const int*)d_in[2];
    const float* c1W1  = (const float*)d_in[3];
    const float* c1b1  = (const float*)d_in[4];
    const float* c1W2  = (const float*)d_in[5];
    const float* c2W1  = (const float*)d_in[6];
    const float* c2b1  = (const float*)d_in[7];
    const float* c2W2  = (const float*)d_in[8];
    const float* l1W   = (const float*)d_in[9];
    const float* l1b   = (const float*)d_in[10];
    const float* l2W   = (const float*)d_in[11];
    const float* l2b   = (const float*)d_in[12];
    float* out = (float*)d_out;

    char* p = (char*)d_ws;
    auto alloc = [&p](size_t bytes) -> void* {
        void* r = (void*)p;
        p += (bytes + 255) & ~(size_t)255;
        return r;
    };
    float*          dinv    = (float*)         alloc(N_NODES * 4);
    float4*         wx      = (float4*)        alloc((size_t)N_NODES * 16);
    float*          center2 = (float*)         alloc((size_t)N_NODES * F * 4);
    __half*         xj2h    = (__half*)        alloc((size_t)N_NODES * F * 2);
    // gpool(4KB) + gcnt(256B) contiguous -> one memset
    float*          gpool   = (float*)         alloc(N_GRAPHS * F * 4);
    int*            gcnt    = (int*)           alloc(N_GRAPHS * 4);
    // bhistC(1KB) + bhistR(1KB) contiguous -> one memset
    int*            bhistC  = (int*)           alloc(NBUCK * 4);
    int*            bhistR  = (int*)           alloc(NBUCK * 4);
    int*            bbaseC  = (int*)           alloc((NBUCK + 1) * 4);
    int*            bbaseR  = (int*)           alloc((NBUCK + 1) * 4);
    int*            cntmatC = (int*)           alloc((size_t)NBUCK * NBLK * 4);
    int*            cntmatR = (int*)           alloc((size_t)NBUCK * NBLK * 4);
    int*            rowptr  = (int*)           alloc((size_t)N_NODES * 4);
    int*            cnt_in  = (int*)           alloc((size_t)N_NODES * 4);
    unsigned*       recsA   = (unsigned*)      alloc(((size_t)N_EDGES + NBUCK * 16) * 4);
    unsigned*       recsB   = (unsigned*)      alloc(((size_t)N_EDGES + NBUCK * 16) * 4);
    unsigned short* rrecs   = (unsigned short*)alloc(((size_t)N_EDGES + NBUCK * 16) * 2);

    hipMemsetAsync(gpool, 0, N_GRAPHS * F * 4 + 256, stream);     // gpool + gcnt
    hipMemsetAsync(bhistC, 0, 2 * NBUCK * 4, stream);             // bhistC + bhistR

    k_histAB<<<NBLK, 256, 0, stream>>>(row, col, cntmatC, cntmatR, bhistC, bhistR);
    k_scans<<<2 * NBUCK + 2, 256, 0, stream>>>(cntmatC, cntmatR, bhistC, bhistR, bbaseC, bbaseR);
    k_fill3<<<NBLK, 256, 0, stream>>>(row, col, cntmatC, cntmatR, bbaseC, bbaseR, recsA, rrecs);
    k_degsort<<<2 * NBUCK, 256, 0, stream>>>(recsA, bbaseC, bhistC, recsB, rowptr, cnt_in,
                                             rrecs, bbaseR, bhistR, x, dinv, wx);
    k_conv1<<<(N_NODES + 255) / 256, 256, 0, stream>>>(recsB, rowptr, cnt_in, dinv, wx, x,
                                                       c1W1, c1b1, c1W2, c2W1, c2b1, c2W2,
                                                       center2, xj2h);
    k_gpool<<<(N_NODES + PCHUNK - 1) / PCHUNK, 1024, 0, stream>>>(
        recsB, rowptr, cnt_in, dinv, xj2h, center2, batch, gpool, gcnt);
    k_mlp<<<1, 64, 0, stream>>>(gpool, gcnt, l1W, l1b, l2W, l2b, out);
}

// Round 11
// 174.891 us; speedup vs baseline: 4.6736x; 1.1889x over previous
//
#include <hip/hip_runtime.h>
#include <hip/hip_fp16.h>

#define N_NODES 100000
#define N_EDGES 3200000
#define N_GRAPHS 64
#define F 16

#define NBUCK 256
#define CPB 391                 // cols per bucket: 256*391 = 100096 >= N_NODES
#define NBLK 256                // sort blocks
#define EPB ((N_EDGES + NBLK - 1) / NBLK)   // 12500 edges per block (exact, %4==0)
#define RMASK 0x1FFFF
#define PCHUNK 64               // nodes per gpool block

// Pass 1: per-block LDS histograms of col/row buckets; int4-vectorized edge reads.
__global__ __launch_bounds__(256) void k_histAB(const int* __restrict__ row,
                                                const int* __restrict__ col,
                                                int* __restrict__ cntmatC,
                                                int* __restrict__ cntmatR,
                                                int* __restrict__ bhistC,
                                                int* __restrict__ bhistR) {
    __shared__ int lhc[NBUCK], lhr[NBUCK];
    for (int i = threadIdx.x; i < NBUCK; i += 256) { lhc[i] = 0; lhr[i] = 0; }
    __syncthreads();
    int beg = blockIdx.x * EPB;                // EPB and beg are multiples of 4
    const int4* r4 = (const int4*)(row + beg);
    const int4* c4 = (const int4*)(col + beg);
    const int n4 = EPB / 4;
    for (int i = threadIdx.x; i < n4; i += 256) {
        int4 r = r4[i], c = c4[i];
        atomicAdd(&lhc[(unsigned)c.x / CPB], 1);
        atomicAdd(&lhc[(unsigned)c.y / CPB], 1);
        atomicAdd(&lhc[(unsigned)c.z / CPB], 1);
        atomicAdd(&lhc[(unsigned)c.w / CPB], 1);
        atomicAdd(&lhr[(unsigned)r.x / CPB], 1);
        atomicAdd(&lhr[(unsigned)r.y / CPB], 1);
        atomicAdd(&lhr[(unsigned)r.z / CPB], 1);
        atomicAdd(&lhr[(unsigned)r.w / CPB], 1);
    }
    __syncthreads();
    for (int i = threadIdx.x; i < NBUCK; i += 256) {
        int c = lhc[i], r = lhr[i];
        cntmatC[i * NBLK + blockIdx.x] = c;
        cntmatR[i * NBLK + blockIdx.x] = r;
        if (c) atomicAdd(&bhistC[i], c);
        if (r) atomicAdd(&bhistR[i], r);
    }
}

// Pass 2 (merged): blocks 0-511 scan cntmat rows; blocks 512/513 scan bucket totals.
__global__ __launch_bounds__(256) void k_scans(int* __restrict__ cntmatC,
                                               int* __restrict__ cntmatR,
                                               const int* __restrict__ bhistC,
                                               const int* __restrict__ bhistR,
                                               int* __restrict__ bbaseC,
                                               int* __restrict__ bbaseR) {
    __shared__ int sd[256];
    int t = threadIdx.x;
    if (blockIdx.x < 2 * NBUCK) {
        int which = blockIdx.x >> 8;
        int b = blockIdx.x & 255;
        int* cm = which ? cntmatR : cntmatC;
        int v = cm[b * NBLK + t];
        sd[t] = v;
        __syncthreads();
        for (int off = 1; off < 256; off <<= 1) {
            int a = (t >= off) ? sd[t - off] : 0;
            __syncthreads();
            sd[t] += a;
            __syncthreads();
        }
        cm[b * NBLK + t] = sd[t] - v;
    } else {
        const int* h = (blockIdx.x == 2 * NBUCK) ? bhistC : bhistR;
        int* o = (blockIdx.x == 2 * NBUCK) ? bbaseC : bbaseR;
        int v = (h[t] + 15) & ~15;
        sd[t] = v;
        __syncthreads();
        for (int off = 1; off < NBUCK; off <<= 1) {
            int a = (t >= off) ? sd[t - off] : 0;
            __syncthreads();
            sd[t] += a;
            __syncthreads();
        }
        o[t] = sd[t] - v;
    }
}

// Pass 3: dual deterministic scatter (int4-vectorized reads)
__global__ __launch_bounds__(256) void k_fill3(const int* __restrict__ row,
                                               const int* __restrict__ col,
                                               const int* __restrict__ cntmatC,
                                               const int* __restrict__ cntmatR,
                                               const int* __restrict__ bbaseC,
                                               const int* __restrict__ bbaseR,
                                               unsigned* __restrict__ recsA,
                                               unsigned short* __restrict__ rrecs) {
    __shared__ int ptrC[NBUCK], ptrR[NBUCK];
    for (int i = threadIdx.x; i < NBUCK; i += 256) {
        ptrC[i] = bbaseC[i] + cntmatC[i * NBLK + blockIdx.x];
        ptrR[i] = bbaseR[i] + cntmatR[i * NBLK + blockIdx.x];
    }
    __syncthreads();
    int beg = blockIdx.x * EPB;
    const int4* r4 = (const int4*)(row + beg);
    const int4* c4 = (const int4*)(col + beg);
    const int n4 = EPB / 4;
    for (int i = threadIdx.x; i < n4; i += 256) {
        int4 rv = r4[i], cv = c4[i];
        int rr[4] = {rv.x, rv.y, rv.z, rv.w};
        int cc[4] = {cv.x, cv.y, cv.z, cv.w};
#pragma unroll
        for (int u = 0; u < 4; ++u) {
            unsigned c = (unsigned)cc[u];
            unsigned r = (unsigned)rr[u];
            unsigned bc = c / CPB;
            int slot = atomicAdd(&ptrC[bc], 1);
            recsA[slot] = ((c - bc * CPB) << 17) | r;
            unsigned br = r / CPB;
            int slotR = atomicAdd(&ptrR[br], 1);
            rrecs[slotR] = (unsigned short)(r - br * CPB);
        }
    }
}

// Pass 4 (merged): blocks 0-255: per-col-bucket counting sort -> recsB + rowptr + cnt_in
//                  blocks 256-511: per-row-bucket degree histogram -> dinv + wx
__global__ __launch_bounds__(256) void k_degsort(const unsigned* __restrict__ recsA,
                                                 const int* __restrict__ bbaseC,
                                                 const int* __restrict__ bhistC,
                                                 unsigned* __restrict__ recsB,
                                                 int* __restrict__ rowptr,
                                                 int* __restrict__ cnt_in,
                                                 const unsigned short* __restrict__ rrecs,
                                                 const int* __restrict__ bbaseR,
                                                 const int* __restrict__ bhistR,
                                                 const float* __restrict__ x,
                                                 float* __restrict__ dinv,
                                                 float4* __restrict__ wx) {
    __shared__ int hist[CPB];
    __shared__ int scn[512];
    __shared__ int off[CPB];
    int t = threadIdx.x;
    if (blockIdx.x < NBUCK) {
        int b = blockIdx.x;
        for (int i = t; i < CPB; i += 256) hist[i] = 0;
        __syncthreads();
        int beg = bbaseC[b], n = bhistC[b];
        for (int i = t; i < n; i += 256)
            atomicAdd(&hist[recsA[beg + i] >> 17], 1);
        __syncthreads();
        scn[t]       = (t < CPB) ? hist[t] : 0;
        scn[t + 256] = (t + 256 < CPB) ? hist[t + 256] : 0;
        __syncthreads();
        for (int o = 1; o < 512; o <<= 1) {
            int v0 = (t >= o) ? scn[t - o] : 0;
            int v1 = (t + 256 >= o) ? scn[t + 256 - o] : 0;
            __syncthreads();
            scn[t] += v0; scn[t + 256] += v1;
            __syncthreads();
        }
        for (int lc = t; lc < CPB; lc += 256) {
            int ex = scn[lc] - hist[lc];
            off[lc] = ex;
            int node = b * CPB + lc;
            if (node < N_NODES) { rowptr[node] = beg + ex; cnt_in[node] = hist[lc]; }
        }
        __syncthreads();
        for (int i = t; i < n; i += 256) {
            unsigned rec = recsA[beg + i];
            int d = atomicAdd(&off[rec >> 17], 1);
            recsB[beg + d] = rec;
        }
    } else {
        int b = blockIdx.x - NBUCK;
        for (int i = t; i < CPB; i += 256) hist[i] = 0;
        __syncthreads();
        int beg = bbaseR[b], n = bhistR[b];
        for (int i = t; i < n; i += 256)
            atomicAdd(&hist[rrecs[beg + i]], 1);
        __syncthreads();
        for (int lc = t; lc < CPB; lc += 256) {
            int node = b * CPB + lc;
            if (node >= N_NODES) continue;
            int d = hist[lc];
            float di = d > 0 ? rsqrtf((float)d) : 0.0f;
            dinv[node] = di;
            wx[node] = make_float4(di * x[node * 3 + 0], di * x[node * 3 + 1],
                                   di * x[node * 3 + 2], 0.0f);
        }
    }
}

// Fused conv1 (4-deep ILP + predicated tail): y = gather(wx), h1 = relu(x@W1+b1+y@W2),
// center2 = h1@W1'+b1' (fp32), xj2 = dinv*h1@W2' stored fp16 (L2-resident)
__global__ __launch_bounds__(256) void k_conv1(const unsigned* __restrict__ recsB,
                                               const int* __restrict__ rowptr,
                                               const int* __restrict__ cnt_in,
                                               const float* __restrict__ dinv,
                                               const float4* __restrict__ wx,
                                               const float* __restrict__ x,
                                               const float* __restrict__ c1W1,
                                               const float* __restrict__ c1b1,
                                               const float* __restrict__ c1W2,
                                               const float* __restrict__ c2W1,
                                               const float* __restrict__ c2b1,
                                               const float* __restrict__ c2W2,
                                               float* __restrict__ center2,
                                               __half* __restrict__ xj2h) {
    int nn = blockIdx.x * blockDim.x + threadIdx.x;
    if (nn >= N_NODES) return;
    int beg = rowptr[nn], c = cnt_in[nn], end = beg + c;
    float a0 = 0.0f, a1 = 0.0f, a2 = 0.0f;
    int j = beg;
    for (; j + 3 < end; j += 4) {
        int r[4];
#pragma unroll
        for (int u = 0; u < 4; ++u) r[u] = recsB[j + u] & RMASK;
        float4 v[4];
#pragma unroll
        for (int u = 0; u < 4; ++u) v[u] = wx[r[u]];
#pragma unroll
        for (int u = 0; u < 4; ++u) { a0 += v[u].x; a1 += v[u].y; a2 += v[u].z; }
    }
    if (j < end) {   // predicated tail (<=3), one round-trip
        int r[3]; bool ok[3];
#pragma unroll
        for (int u = 0; u < 3; ++u) {
            ok[u] = (j + u) < end;
            r[u] = recsB[ok[u] ? j + u : j] & RMASK;
        }
#pragma unroll
        for (int u = 0; u < 3; ++u) {
            if (ok[u]) { float4 v = wx[r[u]]; a0 += v.x; a1 += v.y; a2 += v.z; }
        }
    }
    float sc = dinv[nn] / (float)(c > 1 ? c : 1);
    float y0 = a0 * sc, y1 = a1 * sc, y2 = a2 * sc;
    float x0 = x[nn * 3 + 0], x1 = x[nn * 3 + 1], x2 = x[nn * 3 + 2];
    float h[F];
#pragma unroll
    for (int k = 0; k < F; ++k) {
        float v = c1b1[k]
                + x0 * c1W1[0 * F + k] + x1 * c1W1[1 * F + k] + x2 * c1W1[2 * F + k]
                + y0 * c1W2[0 * F + k] + y1 * c1W2[1 * F + k] + y2 * c1W2[2 * F + k];
        h[k] = v > 0.0f ? v : 0.0f;
    }
    float di = dinv[nn];
    float cc[F];
    union { __half hh[F]; uint4 v4[2]; } u;
#pragma unroll
    for (int k = 0; k < F; ++k) {
        float c2 = c2b1[k];
        float xx = 0.0f;
#pragma unroll
        for (int i = 0; i < F; ++i) {
            c2 += h[i] * c2W1[i * F + k];
            xx += h[i] * c2W2[i * F + k];
        }
        cc[k] = c2;
        u.hh[k] = __float2half_rn(di * xx);
    }
    float4* cd = (float4*)(center2 + nn * F);
#pragma unroll
    for (int q = 0; q < 4; ++q)
        cd[q] = make_float4(cc[q * 4 + 0], cc[q * 4 + 1], cc[q * 4 + 2], cc[q * 4 + 3]);
    uint4* xd = (uint4*)(xj2h + nn * F);
    xd[0] = u.v4[0];
    xd[1] = u.v4[1];
}

// Fused conv2-aggregation + pooling: 1024 threads = 64 nodes x 16 feature-lanes.
// 8-deep independent xj2h loads per iteration + predicated 8-wide tail.
__global__ __launch_bounds__(1024) void k_gpool(const unsigned* __restrict__ recsB,
                                                const int* __restrict__ rowptr,
                                                const int* __restrict__ cnt_in,
                                                const float* __restrict__ dinv,
                                                const __half* __restrict__ xj2h,
                                                const float* __restrict__ center2,
                                                const int* __restrict__ batch,
                                                float* __restrict__ gpool,
                                                int* __restrict__ gcnt) {
    __shared__ float tile[PCHUNK][F + 1];
    __shared__ int bid[PCHUNK];
    int g = threadIdx.x >> 4, k = threadIdx.x & 15;
    int nn = blockIdx.x * PCHUNK + g;
    bool valid = nn < N_NODES;
    float hval = 0.0f;
    if (valid) {
        int beg = rowptr[nn], c = cnt_in[nn], end = beg + c;
        float acc = 0.0f;
        int j = beg;
        for (; j + 7 < end; j += 8) {
            int r[8];
#pragma unroll
            for (int u = 0; u < 8; ++u) r[u] = recsB[j + u] & RMASK;
            float v[8];
#pragma unroll
            for (int u = 0; u < 8; ++u) v[u] = __half2float(xj2h[r[u] * F + k]);
#pragma unroll
            for (int u = 0; u < 8; ++u) acc += v[u];
        }
        if (j < end) {   // predicated tail (<=7), one round-trip
            int r[7]; bool ok[7];
#pragma unroll
            for (int u = 0; u < 7; ++u) {
                ok[u] = (j + u) < end;
                r[u] = recsB[ok[u] ? j + u : j] & RMASK;
            }
#pragma unroll
            for (int u = 0; u < 7; ++u)
                if (ok[u]) acc += __half2float(xj2h[r[u] * F + k]);
        }
        float s2 = acc * dinv[nn] / (float)(c > 1 ? c : 1);
        hval = center2[nn * F + k] + s2;
        hval = hval > 0.0f ? hval : 0.0f;
        if (k == 0) bid[g] = batch[nn];
    } else if (k == 0) {
        bid[g] = -1;
    }
    tile[g][k] = hval;
    __syncthreads();
    if (threadIdx.x < 16) {
        int kk = threadIdx.x;
        int bcur = -2; float acc = 0.0f; int run = 0;
        for (int gg = 0; gg < PCHUNK; ++gg) {
            int b = bid[gg];
            if (b < 0) break;   // tail: invalid nodes only at the end
            if (b != bcur) {
                if (bcur >= 0) {
                    atomicAdd(&gpool[bcur * F + kk], acc);
                    if (kk == 0) atomicAdd(&gcnt[bcur], run);
                }
                acc = 0.0f; run = 0; bcur = b;
            }
            acc += tile[gg][kk];
            ++run;
        }
        if (bcur >= 0) {
            atomicAdd(&gpool[bcur * F + kk], acc);
            if (kk == 0) atomicAdd(&gcnt[bcur], run);
        }
    }
}

__global__ __launch_bounds__(64) void k_mlp(const float* __restrict__ gpool,
                                            const int* __restrict__ gcnt,
                                            const float* __restrict__ l1W,
                                            const float* __restrict__ l1b,
                                            const float* __restrict__ l2W,
                                            const float* __restrict__ l2b,
                                            float* __restrict__ out) {
    int g = threadIdx.x;
    if (g >= N_GRAPHS) return;
    int c = gcnt[g];
    float ic = 1.0f / (float)(c > 1 ? c : 1);
    float v[F], h[F];
#pragma unroll
    for (int k = 0; k < F; ++k) v[k] = gpool[g * F + k] * ic;
#pragma unroll
    for (int k = 0; k < F; ++k) {
        float a = l1b[k];
#pragma unroll
        for (int i = 0; i < F; ++i) a += v[i] * l1W[i * F + k];
        h[k] = a > 0.0f ? a : 0.0f;
    }
#pragma unroll
    for (int j = 0; j < 2; ++j) {
        float a = l2b[j];
#pragma unroll
        for (int i = 0; i < F; ++i) a += h[i] * l2W[i * 2 + j];
        out[g * 2 + j] = a;
    }
}

extern "C" void kernel_launch(void* const* d_in, const int* in_sizes, int n_in,
                              void* d_out, int out_size, void* d_ws, size_t ws_size,
                              hipStream_t stream) {
    const float* x     = (const float*)d_in[0];
    const int*   ei    = (const int*)d_in[1];
    const int*   row   = ei;
    const int*   col   = ei + N_EDGES;
    const int*   batch = (const int*)d_in[2];
    const float* c1W1  = (const float*)d_in[3];
    const float* c1b1  = (const float*)d_in[4];
    const float* c1W2  = (const float*)d_in[5];
    const float* c2W1  = (const float*)d_in[6];
    const float* c2b1  = (const float*)d_in[7];
    const float* c2W2  = (const float*)d_in[8];
    const float* l1W   = (const float*)d_in[9];
    const float* l1b   = (const float*)d_in[10];
    const float* l2W   = (const float*)d_in[11];
    const float* l2b   = (const float*)d_in[12];
    float* out = (float*)d_out;

    char* p = (char*)d_ws;
    auto alloc = [&p](size_t bytes) -> void* {
        void* r = (void*)p;
        p += (bytes + 255) & ~(size_t)255;
        return r;
    };
    float*          dinv    = (float*)         alloc(N_NODES * 4);
    float4*         wx      = (float4*)        alloc((size_t)N_NODES * 16);
    float*          center2 = (float*)         alloc((size_t)N_NODES * F * 4);
    __half*         xj2h    = (__half*)        alloc((size_t)N_NODES * F * 2);
    // gpool(4KB) + gcnt(256B) contiguous -> one memset
    float*          gpool   = (float*)         alloc(N_GRAPHS * F * 4);
    int*            gcnt    = (int*)           alloc(N_GRAPHS * 4);
    // bhistC(1KB) + bhistR(1KB) contiguous -> one memset
    int*            bhistC  = (int*)           alloc(NBUCK * 4);
    int*            bhistR  = (int*)           alloc(NBUCK * 4);
    int*            bbaseC  = (int*)           alloc((NBUCK + 1) * 4);
    int*            bbaseR  = (int*)           alloc((NBUCK + 1) * 4);
    int*            cntmatC = (int*)           alloc((size_t)NBUCK * NBLK * 4);
    int*            cntmatR = (int*)           alloc((size_t)NBUCK * NBLK * 4);
    int*            rowptr  = (int*)           alloc((size_t)N_NODES * 4);
    int*            cnt_in  = (int*)           alloc((size_t)N_NODES * 4);
    unsigned*       recsA   = (unsigned*)      alloc(((size_t)N_EDGES + NBUCK * 16) * 4);
    unsigned*       recsB   = (unsigned*)      alloc(((size_t)N_EDGES + NBUCK * 16) * 4);
    unsigned short* rrecs   = (unsigned short*)alloc(((size_t)N_EDGES + NBUCK * 16) * 2);

    hipMemsetAsync(gpool, 0, N_GRAPHS * F * 4 + 256, stream);     // gpool + gcnt
    hipMemsetAsync(bhistC, 0, 2 * NBUCK * 4, stream);             // bhistC + bhistR

    k_histAB<<<NBLK, 256, 0, stream>>>(row, col, cntmatC, cntmatR, bhistC, bhistR);
    k_scans<<<2 * NBUCK + 2, 256, 0, stream>>>(cntmatC, cntmatR, bhistC, bhistR, bbaseC, bbaseR);
    k_fill3<<<NBLK, 256, 0, stream>>>(row, col, cntmatC, cntmatR, bbaseC, bbaseR, recsA, rrecs);
    k_degsort<<<2 * NBUCK, 256, 0, stream>>>(recsA, bbaseC, bhistC, recsB, rowptr, cnt_in,
                                             rrecs, bbaseR, bhistR, x, dinv, wx);
    k_conv1<<<(N_NODES + 255) / 256, 256, 0, stream>>>(recsB, rowptr, cnt_in, dinv, wx, x,
                                                       c1W1, c1b1, c1W2, c2W1, c2b1, c2W2,
                                                       center2, xj2h);
    k_gpool<<<(N_NODES + PCHUNK - 1) / PCHUNK, 1024, 0, stream>>>(
        recsB, rowptr, cnt_in, dinv, xj2h, center2, batch, gpool, gcnt);
    k_mlp<<<1, 64, 0, stream>>>(gpool, gcnt, l1W, l1b, l2W, l2b, out);
}

// Round 12
// 163.324 us; speedup vs baseline: 5.0046x; 1.0708x over previous
//
#include <hip/hip_runtime.h>
#include <hip/hip_fp16.h>

#define N_NODES 100000
#define N_EDGES 3200000
#define N_GRAPHS 64
#define F 16

#define NBUCK 256
#define CPB 391                 // cols per bucket: 256*391 = 100096 >= N_NODES
#define NBLK 256                // sort blocks
#define EPB ((N_EDGES + NBLK - 1) / NBLK)   // 12500 edges per block (exact, %4==0)
#define RMASK 0x1FFFF
#define PCHUNK 64               // nodes per gpool block

// Pass 1: per-block LDS histograms of col/row buckets; int4-vectorized edge reads.
__global__ __launch_bounds__(256) void k_histAB(const int* __restrict__ row,
                                                const int* __restrict__ col,
                                                int* __restrict__ cntmatC,
                                                int* __restrict__ cntmatR,
                                                int* __restrict__ bhistC,
                                                int* __restrict__ bhistR) {
    __shared__ int lhc[NBUCK], lhr[NBUCK];
    for (int i = threadIdx.x; i < NBUCK; i += 256) { lhc[i] = 0; lhr[i] = 0; }
    __syncthreads();
    int beg = blockIdx.x * EPB;                // EPB and beg are multiples of 4
    const int4* r4 = (const int4*)(row + beg);
    const int4* c4 = (const int4*)(col + beg);
    const int n4 = EPB / 4;
    for (int i = threadIdx.x; i < n4; i += 256) {
        int4 r = r4[i], c = c4[i];
        atomicAdd(&lhc[(unsigned)c.x / CPB], 1);
        atomicAdd(&lhc[(unsigned)c.y / CPB], 1);
        atomicAdd(&lhc[(unsigned)c.z / CPB], 1);
        atomicAdd(&lhc[(unsigned)c.w / CPB], 1);
        atomicAdd(&lhr[(unsigned)r.x / CPB], 1);
        atomicAdd(&lhr[(unsigned)r.y / CPB], 1);
        atomicAdd(&lhr[(unsigned)r.z / CPB], 1);
        atomicAdd(&lhr[(unsigned)r.w / CPB], 1);
    }
    __syncthreads();
    for (int i = threadIdx.x; i < NBUCK; i += 256) {
        int c = lhc[i], r = lhr[i];
        cntmatC[i * NBLK + blockIdx.x] = c;
        cntmatR[i * NBLK + blockIdx.x] = r;
        if (c) atomicAdd(&bhistC[i], c);
        if (r) atomicAdd(&bhistR[i], r);
    }
}

// Pass 2 (merged): blocks 0-511 scan cntmat rows; blocks 512/513 scan bucket totals.
__global__ __launch_bounds__(256) void k_scans(int* __restrict__ cntmatC,
                                               int* __restrict__ cntmatR,
                                               const int* __restrict__ bhistC,
                                               const int* __restrict__ bhistR,
                                               int* __restrict__ bbaseC,
                                               int* __restrict__ bbaseR) {
    __shared__ int sd[256];
    int t = threadIdx.x;
    if (blockIdx.x < 2 * NBUCK) {
        int which = blockIdx.x >> 8;
        int b = blockIdx.x & 255;
        int* cm = which ? cntmatR : cntmatC;
        int v = cm[b * NBLK + t];
        sd[t] = v;
        __syncthreads();
        for (int off = 1; off < 256; off <<= 1) {
            int a = (t >= off) ? sd[t - off] : 0;
            __syncthreads();
            sd[t] += a;
            __syncthreads();
        }
        cm[b * NBLK + t] = sd[t] - v;
    } else {
        const int* h = (blockIdx.x == 2 * NBUCK) ? bhistC : bhistR;
        int* o = (blockIdx.x == 2 * NBUCK) ? bbaseC : bbaseR;
        int v = (h[t] + 15) & ~15;
        sd[t] = v;
        __syncthreads();
        for (int off = 1; off < NBUCK; off <<= 1) {
            int a = (t >= off) ? sd[t - off] : 0;
            __syncthreads();
            sd[t] += a;
            __syncthreads();
        }
        o[t] = sd[t] - v;
    }
}

// Pass 3: dual deterministic scatter (int4-vectorized reads)
__global__ __launch_bounds__(256) void k_fill3(const int* __restrict__ row,
                                               const int* __restrict__ col,
                                               const int* __restrict__ cntmatC,
                                               const int* __restrict__ cntmatR,
                                               const int* __restrict__ bbaseC,
                                               const int* __restrict__ bbaseR,
                                               unsigned* __restrict__ recsA,
                                               unsigned short* __restrict__ rrecs) {
    __shared__ int ptrC[NBUCK], ptrR[NBUCK];
    for (int i = threadIdx.x; i < NBUCK; i += 256) {
        ptrC[i] = bbaseC[i] + cntmatC[i * NBLK + blockIdx.x];
        ptrR[i] = bbaseR[i] + cntmatR[i * NBLK + blockIdx.x];
    }
    __syncthreads();
    int beg = blockIdx.x * EPB;
    const int4* r4 = (const int4*)(row + beg);
    const int4* c4 = (const int4*)(col + beg);
    const int n4 = EPB / 4;
    for (int i = threadIdx.x; i < n4; i += 256) {
        int4 rv = r4[i], cv = c4[i];
        int rr[4] = {rv.x, rv.y, rv.z, rv.w};
        int cc[4] = {cv.x, cv.y, cv.z, cv.w};
#pragma unroll
        for (int u = 0; u < 4; ++u) {
            unsigned c = (unsigned)cc[u];
            unsigned r = (unsigned)rr[u];
            unsigned bc = c / CPB;
            int slot = atomicAdd(&ptrC[bc], 1);
            recsA[slot] = ((c - bc * CPB) << 17) | r;
            unsigned br = r / CPB;
            int slotR = atomicAdd(&ptrR[br], 1);
            rrecs[slotR] = (unsigned short)(r - br * CPB);
        }
    }
}

// Pass 4 (merged): blocks 0-255: per-col-bucket counting sort -> recsB + rowptr + cnt_in
//                  blocks 256-511: per-row-bucket degree histogram -> dinv + wx
__global__ __launch_bounds__(256) void k_degsort(const unsigned* __restrict__ recsA,
                                                 const int* __restrict__ bbaseC,
                                                 const int* __restrict__ bhistC,
                                                 unsigned* __restrict__ recsB,
                                                 int* __restrict__ rowptr,
                                                 int* __restrict__ cnt_in,
                                                 const unsigned short* __restrict__ rrecs,
                                                 const int* __restrict__ bbaseR,
                                                 const int* __restrict__ bhistR,
                                                 const float* __restrict__ x,
                                                 float* __restrict__ dinv,
                                                 float4* __restrict__ wx) {
    __shared__ int hist[CPB];
    __shared__ int scn[512];
    __shared__ int off[CPB];
    int t = threadIdx.x;
    if (blockIdx.x < NBUCK) {
        int b = blockIdx.x;
        for (int i = t; i < CPB; i += 256) hist[i] = 0;
        __syncthreads();
        int beg = bbaseC[b], n = bhistC[b];
        for (int i = t; i < n; i += 256)
            atomicAdd(&hist[recsA[beg + i] >> 17], 1);
        __syncthreads();
        scn[t]       = (t < CPB) ? hist[t] : 0;
        scn[t + 256] = (t + 256 < CPB) ? hist[t + 256] : 0;
        __syncthreads();
        for (int o = 1; o < 512; o <<= 1) {
            int v0 = (t >= o) ? scn[t - o] : 0;
            int v1 = (t + 256 >= o) ? scn[t + 256 - o] : 0;
            __syncthreads();
            scn[t] += v0; scn[t + 256] += v1;
            __syncthreads();
        }
        for (int lc = t; lc < CPB; lc += 256) {
            int ex = scn[lc] - hist[lc];
            off[lc] = ex;
            int node = b * CPB + lc;
            if (node < N_NODES) { rowptr[node] = beg + ex; cnt_in[node] = hist[lc]; }
        }
        __syncthreads();
        for (int i = t; i < n; i += 256) {
            unsigned rec = recsA[beg + i];
            int d = atomicAdd(&off[rec >> 17], 1);
            recsB[beg + d] = rec;
        }
    } else {
        int b = blockIdx.x - NBUCK;
        for (int i = t; i < CPB; i += 256) hist[i] = 0;
        __syncthreads();
        int beg = bbaseR[b], n = bhistR[b];
        for (int i = t; i < n; i += 256)
            atomicAdd(&hist[rrecs[beg + i]], 1);
        __syncthreads();
        for (int lc = t; lc < CPB; lc += 256) {
            int node = b * CPB + lc;
            if (node >= N_NODES) continue;
            int d = hist[lc];
            float di = d > 0 ? rsqrtf((float)d) : 0.0f;
            dinv[node] = di;
            wx[node] = make_float4(di * x[node * 3 + 0], di * x[node * 3 + 1],
                                   di * x[node * 3 + 2], 0.0f);
        }
    }
}

// Fused conv1 (8-deep ILP + predicated tail): y = gather(wx), h1 = relu(x@W1+b1+y@W2),
// center2 = h1@W1'+b1' (fp32), xj2 = dinv*h1@W2' stored fp16 (L2-resident)
__global__ __launch_bounds__(256) void k_conv1(const unsigned* __restrict__ recsB,
                                               const int* __restrict__ rowptr,
                                               const int* __restrict__ cnt_in,
                                               const float* __restrict__ dinv,
                                               const float4* __restrict__ wx,
                                               const float* __restrict__ x,
                                               const float* __restrict__ c1W1,
                                               const float* __restrict__ c1b1,
                                               const float* __restrict__ c1W2,
                                               const float* __restrict__ c2W1,
                                               const float* __restrict__ c2b1,
                                               const float* __restrict__ c2W2,
                                               float* __restrict__ center2,
                                               __half* __restrict__ xj2h) {
    int nn = blockIdx.x * blockDim.x + threadIdx.x;
    if (nn >= N_NODES) return;
    int beg = rowptr[nn], c = cnt_in[nn], end = beg + c;
    float a0 = 0.0f, a1 = 0.0f, a2 = 0.0f;
    int j = beg;
    for (; j + 7 < end; j += 8) {
        int r[8];
#pragma unroll
        for (int u = 0; u < 8; ++u) r[u] = recsB[j + u] & RMASK;
        float4 v[8];
#pragma unroll
        for (int u = 0; u < 8; ++u) v[u] = wx[r[u]];
#pragma unroll
        for (int u = 0; u < 8; ++u) { a0 += v[u].x; a1 += v[u].y; a2 += v[u].z; }
    }
    if (j < end) {   // predicated tail (<=7), one round-trip
        int r[7]; bool ok[7];
#pragma unroll
        for (int u = 0; u < 7; ++u) {
            ok[u] = (j + u) < end;
            r[u] = recsB[ok[u] ? j + u : j] & RMASK;
        }
#pragma unroll
        for (int u = 0; u < 7; ++u) {
            if (ok[u]) { float4 v = wx[r[u]]; a0 += v.x; a1 += v.y; a2 += v.z; }
        }
    }
    float sc = dinv[nn] / (float)(c > 1 ? c : 1);
    float y0 = a0 * sc, y1 = a1 * sc, y2 = a2 * sc;
    float x0 = x[nn * 3 + 0], x1 = x[nn * 3 + 1], x2 = x[nn * 3 + 2];
    float h[F];
#pragma unroll
    for (int k = 0; k < F; ++k) {
        float v = c1b1[k]
                + x0 * c1W1[0 * F + k] + x1 * c1W1[1 * F + k] + x2 * c1W1[2 * F + k]
                + y0 * c1W2[0 * F + k] + y1 * c1W2[1 * F + k] + y2 * c1W2[2 * F + k];
        h[k] = v > 0.0f ? v : 0.0f;
    }
    float di = dinv[nn];
    float cc[F];
    union { __half hh[F]; uint4 v4[2]; } u;
#pragma unroll
    for (int k = 0; k < F; ++k) {
        float c2 = c2b1[k];
        float xx = 0.0f;
#pragma unroll
        for (int i = 0; i < F; ++i) {
            c2 += h[i] * c2W1[i * F + k];
            xx += h[i] * c2W2[i * F + k];
        }
        cc[k] = c2;
        u.hh[k] = __float2half_rn(di * xx);
    }
    float4* cd = (float4*)(center2 + nn * F);
#pragma unroll
    for (int q = 0; q < 4; ++q)
        cd[q] = make_float4(cc[q * 4 + 0], cc[q * 4 + 1], cc[q * 4 + 2], cc[q * 4 + 3]);
    uint4* xd = (uint4*)(xj2h + nn * F);
    xd[0] = u.v4[0];
    xd[1] = u.v4[1];
}

// Fused conv2-aggregation + pooling: 512 threads = 64 nodes x 8 half2-lanes.
// Each wave covers 8 nodes -> 64 records in flight per iteration (2x round 11).
__global__ __launch_bounds__(512) void k_gpool(const unsigned* __restrict__ recsB,
                                               const int* __restrict__ rowptr,
                                               const int* __restrict__ cnt_in,
                                               const float* __restrict__ dinv,
                                               const __half* __restrict__ xj2h,
                                               const float* __restrict__ center2,
                                               const int* __restrict__ batch,
                                               float* __restrict__ gpool,
                                               int* __restrict__ gcnt) {
    __shared__ float tile[PCHUNK][F + 1];
    __shared__ int bid[PCHUNK];
    int g = threadIdx.x >> 3, k2 = threadIdx.x & 7;   // features 2*k2, 2*k2+1
    int nn = blockIdx.x * PCHUNK + g;
    bool valid = nn < N_NODES;
    float acc0 = 0.0f, acc1 = 0.0f;
    float h0 = 0.0f, h1 = 0.0f;
    if (valid) {
        int beg = rowptr[nn], c = cnt_in[nn], end = beg + c;
        int j = beg;
        for (; j + 7 < end; j += 8) {
            int r[8];
#pragma unroll
            for (int u = 0; u < 8; ++u) r[u] = recsB[j + u] & RMASK;
            float2 v[8];
#pragma unroll
            for (int u = 0; u < 8; ++u) {
                __half2 hv = *(const __half2*)(xj2h + r[u] * F + 2 * k2);
                v[u] = __half22float2(hv);
            }
#pragma unroll
            for (int u = 0; u < 8; ++u) { acc0 += v[u].x; acc1 += v[u].y; }
        }
        if (j < end) {   // predicated tail (<=7), one round-trip
            int r[7]; bool ok[7];
#pragma unroll
            for (int u = 0; u < 7; ++u) {
                ok[u] = (j + u) < end;
                r[u] = recsB[ok[u] ? j + u : j] & RMASK;
            }
#pragma unroll
            for (int u = 0; u < 7; ++u) {
                if (ok[u]) {
                    __half2 hv = *(const __half2*)(xj2h + r[u] * F + 2 * k2);
                    float2 v = __half22float2(hv);
                    acc0 += v.x; acc1 += v.y;
                }
            }
        }
        float sc = dinv[nn] / (float)(c > 1 ? c : 1);
        float2 ctr = *(const float2*)(center2 + nn * F + 2 * k2);
        h0 = ctr.x + acc0 * sc; h0 = h0 > 0.0f ? h0 : 0.0f;
        h1 = ctr.y + acc1 * sc; h1 = h1 > 0.0f ? h1 : 0.0f;
        if (k2 == 0) bid[g] = batch[nn];
    } else if (k2 == 0) {
        bid[g] = -1;
    }
    tile[g][2 * k2]     = h0;
    tile[g][2 * k2 + 1] = h1;
    __syncthreads();
    if (threadIdx.x < 16) {
        int kk = threadIdx.x;
        int bcur = -2; float acc = 0.0f; int run = 0;
        for (int gg = 0; gg < PCHUNK; ++gg) {
            int b = bid[gg];
            if (b < 0) break;   // tail: invalid nodes only at the end
            if (b != bcur) {
                if (bcur >= 0) {
                    atomicAdd(&gpool[bcur * F + kk], acc);
                    if (kk == 0) atomicAdd(&gcnt[bcur], run);
                }
                acc = 0.0f; run = 0; bcur = b;
            }
            acc += tile[gg][kk];
            ++run;
        }
        if (bcur >= 0) {
            atomicAdd(&gpool[bcur * F + kk], acc);
            if (kk == 0) atomicAdd(&gcnt[bcur], run);
        }
    }
}

__global__ __launch_bounds__(64) void k_mlp(const float* __restrict__ gpool,
                                            const int* __restrict__ gcnt,
                                            const float* __restrict__ l1W,
                                            const float* __restrict__ l1b,
                                            const float* __restrict__ l2W,
                                            const float* __restrict__ l2b,
                                            float* __restrict__ out) {
    int g = threadIdx.x;
    if (g >= N_GRAPHS) return;
    int c = gcnt[g];
    float ic = 1.0f / (float)(c > 1 ? c : 1);
    float v[F], h[F];
#pragma unroll
    for (int k = 0; k < F; ++k) v[k] = gpool[g * F + k] * ic;
#pragma unroll
    for (int k = 0; k < F; ++k) {
        float a = l1b[k];
#pragma unroll
        for (int i = 0; i < F; ++i) a += v[i] * l1W[i * F + k];
        h[k] = a > 0.0f ? a : 0.0f;
    }
#pragma unroll
    for (int j = 0; j < 2; ++j) {
        float a = l2b[j];
#pragma unroll
        for (int i = 0; i < F; ++i) a += h[i] * l2W[i * 2 + j];
        out[g * 2 + j] = a;
    }
}

extern "C" void kernel_launch(void* const* d_in, const int* in_sizes, int n_in,
                              void* d_out, int out_size, void* d_ws, size_t ws_size,
                              hipStream_t stream) {
    const float* x     = (const float*)d_in[0];
    const int*   ei    = (const int*)d_in[1];
    const int*   row   = ei;
    const int*   col   = ei + N_EDGES;
    const int*   batch = (const int*)d_in[2];
    const float* c1W1  = (const float*)d_in[3];
    const float* c1b1  = (const float*)d_in[4];
    const float* c1W2  = (const float*)d_in[5];
    const float* c2W1  = (const float*)d_in[6];
    const float* c2b1  = (const float*)d_in[7];
    const float* c2W2  = (const float*)d_in[8];
    const float* l1W   = (const float*)d_in[9];
    const float* l1b   = (const float*)d_in[10];
    const float* l2W   = (const float*)d_in[11];
    const float* l2b   = (const float*)d_in[12];
    float* out = (float*)d_out;

    char* p = (char*)d_ws;
    auto alloc = [&p](size_t bytes) -> void* {
        void* r = (void*)p;
        p += (bytes + 255) & ~(size_t)255;
        return r;
    };
    float*          dinv    = (float*)         alloc(N_NODES * 4);
    float4*         wx      = (float4*)        alloc((size_t)N_NODES * 16);
    float*          center2 = (float*)         alloc((size_t)N_NODES * F * 4);
    __half*         xj2h    = (__half*)        alloc((size_t)N_NODES * F * 2);
    // gpool(4KB) + gcnt(256B) contiguous -> one memset
    float*          gpool   = (float*)         alloc(N_GRAPHS * F * 4);
    int*            gcnt    = (int*)           alloc(N_GRAPHS * 4);
    // bhistC(1KB) + bhistR(1KB) contiguous -> one memset
    int*            bhistC  = (int*)           alloc(NBUCK * 4);
    int*            bhistR  = (int*)           alloc(NBUCK * 4);
    int*            bbaseC  = (int*)           alloc((NBUCK + 1) * 4);
    int*            bbaseR  = (int*)           alloc((NBUCK + 1) * 4);
    int*            cntmatC = (int*)           alloc((size_t)NBUCK * NBLK * 4);
    int*            cntmatR = (int*)           alloc((size_t)NBUCK * NBLK * 4);
    int*            rowptr  = (int*)           alloc((size_t)N_NODES * 4);
    int*            cnt_in  = (int*)           alloc((size_t)N_NODES * 4);
    unsigned*       recsA   = (unsigned*)      alloc(((size_t)N_EDGES + NBUCK * 16) * 4);
    unsigned*       recsB   = (unsigned*)      alloc(((size_t)N_EDGES + NBUCK * 16) * 4);
    unsigned short* rrecs   = (unsigned short*)alloc(((size_t)N_EDGES + NBUCK * 16) * 2);

    hipMemsetAsync(gpool, 0, N_GRAPHS * F * 4 + 256, stream);     // gpool + gcnt
    hipMemsetAsync(bhistC, 0, 2 * NBUCK * 4, stream);             // bhistC + bhistR

    k_histAB<<<NBLK, 256, 0, stream>>>(row, col, cntmatC, cntmatR, bhistC, bhistR);
    k_scans<<<2 * NBUCK + 2, 256, 0, stream>>>(cntmatC, cntmatR, bhistC, bhistR, bbaseC, bbaseR);
    k_fill3<<<NBLK, 256, 0, stream>>>(row, col, cntmatC, cntmatR, bbaseC, bbaseR, recsA, rrecs);
    k_degsort<<<2 * NBUCK, 256, 0, stream>>>(recsA, bbaseC, bhistC, recsB, rowptr, cnt_in,
                                             rrecs, bbaseR, bhistR, x, dinv, wx);
    k_conv1<<<(N_NODES + 255) / 256, 256, 0, stream>>>(recsB, rowptr, cnt_in, dinv, wx, x,
                                                       c1W1, c1b1, c1W2, c2W1, c2b1, c2W2,
                                                       center2, xj2h);
    k_gpool<<<(N_NODES + PCHUNK - 1) / PCHUNK, 512, 0, stream>>>(
        recsB, rowptr, cnt_in, dinv, xj2h, center2, batch, gpool, gcnt);
    k_mlp<<<1, 64, 0, stream>>>(gpool, gcnt, l1W, l1b, l2W, l2b, out);
}

// Round 13
// 147.501 us; speedup vs baseline: 5.5414x; 1.1073x over previous
//
#include <hip/hip_runtime.h>
#include <hip/hip_fp16.h>

#define N_NODES 100000
#define N_EDGES 3200000
#define N_GRAPHS 64
#define F 16

#define NBUCK 256
#define CPB 391                 // cols per bucket: 256*391 = 100096 >= N_NODES
#define NBLK 256                // fill segments (write-amp structure)
#define EPB ((N_EDGES + NBLK - 1) / NBLK)   // 12500 edges per block (exact, %4==0)
#define RMASK 0x1FFFF
#define PCHUNK 64               // nodes per gpool block

// Pass 1: per-block LDS histograms of col/row buckets; 1024 threads for latency hiding.
__global__ __launch_bounds__(1024) void k_histAB(const int* __restrict__ row,
                                                 const int* __restrict__ col,
                                                 int* __restrict__ cntmatC,
                                                 int* __restrict__ cntmatR,
                                                 int* __restrict__ bhistC,
                                                 int* __restrict__ bhistR) {
    __shared__ int lhc[NBUCK], lhr[NBUCK];
    for (int i = threadIdx.x; i < NBUCK; i += 1024) { lhc[i] = 0; lhr[i] = 0; }
    __syncthreads();
    int beg = blockIdx.x * EPB;                // EPB and beg are multiples of 4
    const int4* r4 = (const int4*)(row + beg);
    const int4* c4 = (const int4*)(col + beg);
    const int n4 = EPB / 4;
    for (int i = threadIdx.x; i < n4; i += 1024) {
        int4 r = r4[i], c = c4[i];
        atomicAdd(&lhc[(unsigned)c.x / CPB], 1);
        atomicAdd(&lhc[(unsigned)c.y / CPB], 1);
        atomicAdd(&lhc[(unsigned)c.z / CPB], 1);
        atomicAdd(&lhc[(unsigned)c.w / CPB], 1);
        atomicAdd(&lhr[(unsigned)r.x / CPB], 1);
        atomicAdd(&lhr[(unsigned)r.y / CPB], 1);
        atomicAdd(&lhr[(unsigned)r.z / CPB], 1);
        atomicAdd(&lhr[(unsigned)r.w / CPB], 1);
    }
    __syncthreads();
    for (int i = threadIdx.x; i < NBUCK; i += 1024) {
        int c = lhc[i], r = lhr[i];
        cntmatC[i * NBLK + blockIdx.x] = c;
        cntmatR[i * NBLK + blockIdx.x] = r;
        if (c) atomicAdd(&bhistC[i], c);
        if (r) atomicAdd(&bhistR[i], r);
    }
}

// Pass 2 (merged): blocks 0-511 scan cntmat rows; blocks 512/513 scan bucket totals.
__global__ __launch_bounds__(256) void k_scans(int* __restrict__ cntmatC,
                                               int* __restrict__ cntmatR,
                                               const int* __restrict__ bhistC,
                                               const int* __restrict__ bhistR,
                                               int* __restrict__ bbaseC,
                                               int* __restrict__ bbaseR) {
    __shared__ int sd[256];
    int t = threadIdx.x;
    if (blockIdx.x < 2 * NBUCK) {
        int which = blockIdx.x >> 8;
        int b = blockIdx.x & 255;
        int* cm = which ? cntmatR : cntmatC;
        int v = cm[b * NBLK + t];
        sd[t] = v;
        __syncthreads();
        for (int off = 1; off < 256; off <<= 1) {
            int a = (t >= off) ? sd[t - off] : 0;
            __syncthreads();
            sd[t] += a;
            __syncthreads();
        }
        cm[b * NBLK + t] = sd[t] - v;
    } else {
        const int* h = (blockIdx.x == 2 * NBUCK) ? bhistC : bhistR;
        int* o = (blockIdx.x == 2 * NBUCK) ? bbaseC : bbaseR;
        int v = (h[t] + 15) & ~15;
        sd[t] = v;
        __syncthreads();
        for (int off = 1; off < NBUCK; off <<= 1) {
            int a = (t >= off) ? sd[t - off] : 0;
            __syncthreads();
            sd[t] += a;
            __syncthreads();
        }
        o[t] = sd[t] - v;
    }
}

// Pass 3: dual deterministic scatter (int4 reads, 1024 threads for store-latency hiding)
__global__ __launch_bounds__(1024) void k_fill3(const int* __restrict__ row,
                                                const int* __restrict__ col,
                                                const int* __restrict__ cntmatC,
                                                const int* __restrict__ cntmatR,
                                                const int* __restrict__ bbaseC,
                                                const int* __restrict__ bbaseR,
                                                unsigned* __restrict__ recsA,
                                                unsigned short* __restrict__ rrecs) {
    __shared__ int ptrC[NBUCK], ptrR[NBUCK];
    for (int i = threadIdx.x; i < NBUCK; i += 1024) {
        ptrC[i] = bbaseC[i] + cntmatC[i * NBLK + blockIdx.x];
        ptrR[i] = bbaseR[i] + cntmatR[i * NBLK + blockIdx.x];
    }
    __syncthreads();
    int beg = blockIdx.x * EPB;
    const int4* r4 = (const int4*)(row + beg);
    const int4* c4 = (const int4*)(col + beg);
    const int n4 = EPB / 4;
    for (int i = threadIdx.x; i < n4; i += 1024) {
        int4 rv = r4[i], cv = c4[i];
        int rr[4] = {rv.x, rv.y, rv.z, rv.w};
        int cc[4] = {cv.x, cv.y, cv.z, cv.w};
#pragma unroll
        for (int u = 0; u < 4; ++u) {
            unsigned c = (unsigned)cc[u];
            unsigned r = (unsigned)rr[u];
            unsigned bc = c / CPB;
            int slot = atomicAdd(&ptrC[bc], 1);
            recsA[slot] = ((c - bc * CPB) << 17) | r;
            unsigned br = r / CPB;
            int slotR = atomicAdd(&ptrR[br], 1);
            rrecs[slotR] = (unsigned short)(r - br * CPB);
        }
    }
}

// Pass 4 (merged, 512 threads): blocks 0-255: per-col-bucket counting sort -> recsB/rowptr/cnt_in
//                               blocks 256-511: per-row-bucket degree histogram -> dinv + wx
__global__ __launch_bounds__(512) void k_degsort(const unsigned* __restrict__ recsA,
                                                 const int* __restrict__ bbaseC,
                                                 const int* __restrict__ bhistC,
                                                 unsigned* __restrict__ recsB,
                                                 int* __restrict__ rowptr,
                                                 int* __restrict__ cnt_in,
                                                 const unsigned short* __restrict__ rrecs,
                                                 const int* __restrict__ bbaseR,
                                                 const int* __restrict__ bhistR,
                                                 const float* __restrict__ x,
                                                 float* __restrict__ dinv,
                                                 float4* __restrict__ wx) {
    __shared__ int hist[CPB];
    __shared__ int scn[512];
    __shared__ int off[CPB];
    int t = threadIdx.x;
    if (blockIdx.x < NBUCK) {
        int b = blockIdx.x;
        if (t < CPB) hist[t] = 0;
        __syncthreads();
        int beg = bbaseC[b], n = bhistC[b];
        for (int i = t; i < n; i += 512)
            atomicAdd(&hist[recsA[beg + i] >> 17], 1);
        __syncthreads();
        int v = (t < CPB) ? hist[t] : 0;
        scn[t] = v;
        __syncthreads();
        for (int o = 1; o < 512; o <<= 1) {
            int a = (t >= o) ? scn[t - o] : 0;
            __syncthreads();
            scn[t] += a;
            __syncthreads();
        }
        if (t < CPB) {
            int ex = scn[t] - v;
            off[t] = ex;
            int node = b * CPB + t;
            if (node < N_NODES) { rowptr[node] = beg + ex; cnt_in[node] = v; }
        }
        __syncthreads();
        for (int i = t; i < n; i += 512) {
            unsigned rec = recsA[beg + i];
            int d = atomicAdd(&off[rec >> 17], 1);
            recsB[beg + d] = rec;
        }
    } else {
        int b = blockIdx.x - NBUCK;
        if (t < CPB) hist[t] = 0;
        __syncthreads();
        int beg = bbaseR[b], n = bhistR[b];
        for (int i = t; i < n; i += 512)
            atomicAdd(&hist[rrecs[beg + i]], 1);
        __syncthreads();
        if (t < CPB) {
            int node = b * CPB + t;
            if (node < N_NODES) {
                int d = hist[t];
                float di = d > 0 ? rsqrtf((float)d) : 0.0f;
                dinv[node] = di;
                wx[node] = make_float4(di * x[node * 3 + 0], di * x[node * 3 + 1],
                                       di * x[node * 3 + 2], 0.0f);
            }
        }
    }
}

// Fused conv1 (8-deep ILP + predicated tail): y = gather(wx), h1 = relu(x@W1+b1+y@W2),
// center2 = h1@W1'+b1' (fp32), xj2 = dinv*h1@W2' stored fp16 (L2-resident)
__global__ __launch_bounds__(256) void k_conv1(const unsigned* __restrict__ recsB,
                                               const int* __restrict__ rowptr,
                                               const int* __restrict__ cnt_in,
                                               const float* __restrict__ dinv,
                                               const float4* __restrict__ wx,
                                               const float* __restrict__ x,
                                               const float* __restrict__ c1W1,
                                               const float* __restrict__ c1b1,
                                               const float* __restrict__ c1W2,
                                               const float* __restrict__ c2W1,
                                               const float* __restrict__ c2b1,
                                               const float* __restrict__ c2W2,
                                               float* __restrict__ center2,
                                               __half* __restrict__ xj2h) {
    int nn = blockIdx.x * blockDim.x + threadIdx.x;
    if (nn >= N_NODES) return;
    int beg = rowptr[nn], c = cnt_in[nn], end = beg + c;
    float a0 = 0.0f, a1 = 0.0f, a2 = 0.0f;
    int j = beg;
    for (; j + 7 < end; j += 8) {
        int r[8];
#pragma unroll
        for (int u = 0; u < 8; ++u) r[u] = recsB[j + u] & RMASK;
        float4 v[8];
#pragma unroll
        for (int u = 0; u < 8; ++u) v[u] = wx[r[u]];
#pragma unroll
        for (int u = 0; u < 8; ++u) { a0 += v[u].x; a1 += v[u].y; a2 += v[u].z; }
    }
    if (j < end) {   // predicated tail (<=7), one round-trip
        int r[7]; bool ok[7];
#pragma unroll
        for (int u = 0; u < 7; ++u) {
            ok[u] = (j + u) < end;
            r[u] = recsB[ok[u] ? j + u : j] & RMASK;
        }
#pragma unroll
        for (int u = 0; u < 7; ++u) {
            if (ok[u]) { float4 v = wx[r[u]]; a0 += v.x; a1 += v.y; a2 += v.z; }
        }
    }
    float sc = dinv[nn] / (float)(c > 1 ? c : 1);
    float y0 = a0 * sc, y1 = a1 * sc, y2 = a2 * sc;
    float x0 = x[nn * 3 + 0], x1 = x[nn * 3 + 1], x2 = x[nn * 3 + 2];
    float h[F];
#pragma unroll
    for (int k = 0; k < F; ++k) {
        float v = c1b1[k]
                + x0 * c1W1[0 * F + k] + x1 * c1W1[1 * F + k] + x2 * c1W1[2 * F + k]
                + y0 * c1W2[0 * F + k] + y1 * c1W2[1 * F + k] + y2 * c1W2[2 * F + k];
        h[k] = v > 0.0f ? v : 0.0f;
    }
    float di = dinv[nn];
    float cc[F];
    union { __half hh[F]; uint4 v4[2]; } u;
#pragma unroll
    for (int k = 0; k < F; ++k) {
        float c2 = c2b1[k];
        float xx = 0.0f;
#pragma unroll
        for (int i = 0; i < F; ++i) {
            c2 += h[i] * c2W1[i * F + k];
            xx += h[i] * c2W2[i * F + k];
        }
        cc[k] = c2;
        u.hh[k] = __float2half_rn(di * xx);
    }
    float4* cd = (float4*)(center2 + nn * F);
#pragma unroll
    for (int q = 0; q < 4; ++q)
        cd[q] = make_float4(cc[q * 4 + 0], cc[q * 4 + 1], cc[q * 4 + 2], cc[q * 4 + 3]);
    uint4* xd = (uint4*)(xj2h + nn * F);
    xd[0] = u.v4[0];
    xd[1] = u.v4[1];
}

// Fused conv2-aggregation + pooling: 512 threads = 64 nodes x 8 half2-lanes.
__global__ __launch_bounds__(512) void k_gpool(const unsigned* __restrict__ recsB,
                                               const int* __restrict__ rowptr,
                                               const int* __restrict__ cnt_in,
                                               const float* __restrict__ dinv,
                                               const __half* __restrict__ xj2h,
                                               const float* __restrict__ center2,
                                               const int* __restrict__ batch,
                                               float* __restrict__ gpool,
                                               int* __restrict__ gcnt) {
    __shared__ float tile[PCHUNK][F + 1];
    __shared__ int bid[PCHUNK];
    int g = threadIdx.x >> 3, k2 = threadIdx.x & 7;   // features 2*k2, 2*k2+1
    int nn = blockIdx.x * PCHUNK + g;
    bool valid = nn < N_NODES;
    float acc0 = 0.0f, acc1 = 0.0f;
    float h0 = 0.0f, h1 = 0.0f;
    if (valid) {
        int beg = rowptr[nn], c = cnt_in[nn], end = beg + c;
        int j = beg;
        for (; j + 7 < end; j += 8) {
            int r[8];
#pragma unroll
            for (int u = 0; u < 8; ++u) r[u] = recsB[j + u] & RMASK;
            float2 v[8];
#pragma unroll
            for (int u = 0; u < 8; ++u) {
                __half2 hv = *(const __half2*)(xj2h + r[u] * F + 2 * k2);
                v[u] = __half22float2(hv);
            }
#pragma unroll
            for (int u = 0; u < 8; ++u) { acc0 += v[u].x; acc1 += v[u].y; }
        }
        if (j < end) {   // predicated tail (<=7), one round-trip
            int r[7]; bool ok[7];
#pragma unroll
            for (int u = 0; u < 7; ++u) {
                ok[u] = (j + u) < end;
                r[u] = recsB[ok[u] ? j + u : j] & RMASK;
            }
#pragma unroll
            for (int u = 0; u < 7; ++u) {
                if (ok[u]) {
                    __half2 hv = *(const __half2*)(xj2h + r[u] * F + 2 * k2);
                    float2 v = __half22float2(hv);
                    acc0 += v.x; acc1 += v.y;
                }
            }
        }
        float sc = dinv[nn] / (float)(c > 1 ? c : 1);
        float2 ctr = *(const float2*)(center2 + nn * F + 2 * k2);
        h0 = ctr.x + acc0 * sc; h0 = h0 > 0.0f ? h0 : 0.0f;
        h1 = ctr.y + acc1 * sc; h1 = h1 > 0.0f ? h1 : 0.0f;
        if (k2 == 0) bid[g] = batch[nn];
    } else if (k2 == 0) {
        bid[g] = -1;
    }
    tile[g][2 * k2]     = h0;
    tile[g][2 * k2 + 1] = h1;
    __syncthreads();
    if (threadIdx.x < 16) {
        int kk = threadIdx.x;
        int bcur = -2; float acc = 0.0f; int run = 0;
        for (int gg = 0; gg < PCHUNK; ++gg) {
            int b = bid[gg];
            if (b < 0) break;   // tail: invalid nodes only at the end
            if (b != bcur) {
                if (bcur >= 0) {
                    atomicAdd(&gpool[bcur * F + kk], acc);
                    if (kk == 0) atomicAdd(&gcnt[bcur], run);
                }
                acc = 0.0f; run = 0; bcur = b;
            }
            acc += tile[gg][kk];
            ++run;
        }
        if (bcur >= 0) {
            atomicAdd(&gpool[bcur * F + kk], acc);
            if (kk == 0) atomicAdd(&gcnt[bcur], run);
        }
    }
}

__global__ __launch_bounds__(64) void k_mlp(const float* __restrict__ gpool,
                                            const int* __restrict__ gcnt,
                                            const float* __restrict__ l1W,
                                            const float* __restrict__ l1b,
                                            const float* __restrict__ l2W,
                                            const float* __restrict__ l2b,
                                            float* __restrict__ out) {
    int g = threadIdx.x;
    if (g >= N_GRAPHS) return;
    int c = gcnt[g];
    float ic = 1.0f / (float)(c > 1 ? c : 1);
    float v[F], h[F];
#pragma unroll
    for (int k = 0; k < F; ++k) v[k] = gpool[g * F + k] * ic;
#pragma unroll
    for (int k = 0; k < F; ++k) {
        float a = l1b[k];
#pragma unroll
        for (int i = 0; i < F; ++i) a += v[i] * l1W[i * F + k];
        h[k] = a > 0.0f ? a : 0.0f;
    }
#pragma unroll
    for (int j = 0; j < 2; ++j) {
        float a = l2b[j];
#pragma unroll
        for (int i = 0; i < F; ++i) a += h[i] * l2W[i * 2 + j];
        out[g * 2 + j] = a;
    }
}

extern "C" void kernel_launch(void* const* d_in, const int* in_sizes, int n_in,
                              void* d_out, int out_size, void* d_ws, size_t ws_size,
                              hipStream_t stream) {
    const float* x     = (const float*)d_in[0];
    const int*   ei    = (const int*)d_in[1];
    const int*   row   = ei;
    const int*   col   = ei + N_EDGES;
    const int*   batch = (const int*)d_in[2];
    const float* c1W1  = (const float*)d_in[3];
    const float* c1b1  = (const float*)d_in[4];
    const float* c1W2  = (const float*)d_in[5];
    const float* c2W1  = (const float*)d_in[6];
    const float* c2b1  = (const float*)d_in[7];
    const float* c2W2  = (const float*)d_in[8];
    const float* l1W   = (const float*)d_in[9];
    const float* l1b   = (const float*)d_in[10];
    const float* l2W   = (const float*)d_in[11];
    const float* l2b   = (const float*)d_in[12];
    float* out = (float*)d_out;

    char* p = (char*)d_ws;
    auto alloc = [&p](size_t bytes) -> void* {
        void* r = (void*)p;
        p += (bytes + 255) & ~(size_t)255;
        return r;
    };
    float*          dinv    = (float*)         alloc(N_NODES * 4);
    float4*         wx      = (float4*)        alloc((size_t)N_NODES * 16);
    float*          center2 = (float*)         alloc((size_t)N_NODES * F * 4);
    __half*         xj2h    = (__half*)        alloc((size_t)N_NODES * F * 2);
    // gpool(4KB) + gcnt(256B) contiguous -> one memset
    float*          gpool   = (float*)         alloc(N_GRAPHS * F * 4);
    int*            gcnt    = (int*)           alloc(N_GRAPHS * 4);
    // bhistC(1KB) + bhistR(1KB) contiguous -> one memset
    int*            bhistC  = (int*)           alloc(NBUCK * 4);
    int*            bhistR  = (int*)           alloc(NBUCK * 4);
    int*            bbaseC  = (int*)           alloc((NBUCK + 1) * 4);
    int*            bbaseR  = (int*)           alloc((NBUCK + 1) * 4);
    int*            cntmatC = (int*)           alloc((size_t)NBUCK * NBLK * 4);
    int*            cntmatR = (int*)           alloc((size_t)NBUCK * NBLK * 4);
    int*            rowptr  = (int*)           alloc((size_t)N_NODES * 4);
    int*            cnt_in  = (int*)           alloc((size_t)N_NODES * 4);
    unsigned*       recsA   = (unsigned*)      alloc(((size_t)N_EDGES + NBUCK * 16) * 4);
    unsigned*       recsB   = (unsigned*)      alloc(((size_t)N_EDGES + NBUCK * 16) * 4);
    unsigned short* rrecs   = (unsigned short*)alloc(((size_t)N_EDGES + NBUCK * 16) * 2);

    hipMemsetAsync(gpool, 0, N_GRAPHS * F * 4 + 256, stream);     // gpool + gcnt
    hipMemsetAsync(bhistC, 0, 2 * NBUCK * 4, stream);             // bhistC + bhistR

    k_histAB<<<NBLK, 1024, 0, stream>>>(row, col, cntmatC, cntmatR, bhistC, bhistR);
    k_scans<<<2 * NBUCK + 2, 256, 0, stream>>>(cntmatC, cntmatR, bhistC, bhistR, bbaseC, bbaseR);
    k_fill3<<<NBLK, 1024, 0, stream>>>(row, col, cntmatC, cntmatR, bbaseC, bbaseR, recsA, rrecs);
    k_degsort<<<2 * NBUCK, 512, 0, stream>>>(recsA, bbaseC, bhistC, recsB, rowptr, cnt_in,
                                             rrecs, bbaseR, bhistR, x, dinv, wx);
    k_conv1<<<(N_NODES + 255) / 256, 256, 0, stream>>>(recsB, rowptr, cnt_in, dinv, wx, x,
                                                       c1W1, c1b1, c1W2, c2W1, c2b1, c2W2,
                                                       center2, xj2h);
    k_gpool<<<(N_NODES + PCHUNK - 1) / PCHUNK, 512, 0, stream>>>(
        recsB, rowptr, cnt_in, dinv, xj2h, center2, batch, gpool, gcnt);
    k_mlp<<<1, 64, 0, stream>>>(gpool, gcnt, l1W, l1b, l2W, l2b, out);
}